// Round 7
// baseline (183.691 us; speedup 1.0000x reference)
//
#include <hip/hip_runtime.h>

#define NT 32768
#define DI 36
#define HH 64
#define G3 192
#define LH 20

typedef __attribute__((ext_vector_type(8))) short bf16x8;
typedef __attribute__((ext_vector_type(4))) float f32x4;
typedef __attribute__((ext_vector_type(4))) int int4v;
union frag_cast { int4v i4; bf16x8 h8; };

__device__ __forceinline__ unsigned f2u(float f) { union { float f; unsigned u; } x; x.f = f; return x.u; }
__device__ __forceinline__ float u2f(unsigned u) { union { float f; unsigned u; } x; x.u = u; return x.f; }
__device__ __forceinline__ unsigned short f2bf_rne(float f) {
    union { float f; unsigned u; } x; x.f = f;
    unsigned r = x.u + 0x7FFFu + ((x.u >> 16) & 1u);
    return (unsigned short)(r >> 16);
}
__device__ __forceinline__ float fast_sigmoid(float x) {
    return __builtin_amdgcn_rcpf(1.f + __builtin_amdgcn_exp2f(-1.44269504089f * x));
}
__device__ __forceinline__ float fast_tanh(float x) {
    return 1.f - 2.f * __builtin_amdgcn_rcpf(1.f + __builtin_amdgcn_exp2f(2.88539008178f * x));
}

// Kernel 1: gi2[t][j] = emb[t,:].W_ih[j,:] + b_ih[j] + (j<128 ? b_hh[j] : 0)
// t-major. Blocks 0..23 emit W_hh hi-fragments (RNE bf16).
// Fragment convention (verified R3): A[m=16mt+(l&15)][k=32kt+8(l>>4)+jj].
__global__ __launch_bounds__(192, 2) void prep_kernel(
    const float* __restrict__ emb, const float* __restrict__ W_ih,
    const float* __restrict__ b_ih, const float* __restrict__ b_hh,
    const float* __restrict__ W_hh,
    float* __restrict__ gi2, int4v* __restrict__ wfrag)
{
    __shared__ float L[DI * 193 + DI * 36];
    float* const Wt = L;              // [k][j]  stride 193
    float* const Et = L + DI * 193;   // [k][ti] stride 36
    const int tid = threadIdx.x;
    const int t0 = blockIdx.x * 32;

    for (int i = tid; i < G3 * DI; i += 192)
        Wt[(i % DI) * 193 + i / DI] = W_ih[i];
    for (int i = tid; i < 32 * DI; i += 192)
        Et[(i % DI) * 36 + i / DI] = emb[(size_t)t0 * DI + i];
    __syncthreads();

    float acc[32];
#pragma unroll
    for (int i = 0; i < 32; ++i) acc[i] = 0.f;
    for (int k = 0; k < DI; ++k) {
        const float w = Wt[k * 193 + tid];
#pragma unroll
        for (int i4 = 0; i4 < 8; ++i4) {
            const float4 e = *(const float4*)&Et[k * 36 + i4 * 4];  // broadcast
            acc[i4 * 4 + 0] = fmaf(e.x, w, acc[i4 * 4 + 0]);
            acc[i4 * 4 + 1] = fmaf(e.y, w, acc[i4 * 4 + 1]);
            acc[i4 * 4 + 2] = fmaf(e.z, w, acc[i4 * 4 + 2]);
            acc[i4 * 4 + 3] = fmaf(e.w, w, acc[i4 * 4 + 3]);
        }
    }
    const float bias = b_ih[tid] + (tid < 128 ? b_hh[tid] : 0.f);
#pragma unroll
    for (int i = 0; i < 32; ++i)
        gi2[(size_t)(t0 + i) * G3 + tid] = acc[i] + bias;   // 768B/row coalesced

    if (blockIdx.x < 24 && tid < 64) {
        const int mt = (int)blockIdx.x >> 1, kt = (int)blockIdx.x & 1;
        const int m = mt * 16 + (tid & 15);
        const int k0 = kt * 32 + (tid >> 4) * 8;
        unsigned short e[8];
#pragma unroll
        for (int jj = 0; jj < 8; ++jj)
            e[jj] = f2bf_rne(W_hh[m * HH + k0 + jj]);
        int4v p;
        p.x = e[0] | ((unsigned)e[1] << 16); p.y = e[2] | ((unsigned)e[3] << 16);
        p.z = e[4] | ((unsigned)e[5] << 16); p.w = e[6] | ((unsigned)e[7] << 16);
        wfrag[(int)blockIdx.x * 64 + tid] = p;
    }
}

// Main kernel: 2048 blocks x 128 thr (2 waves) = one 16-t group per block.
// j-SPLIT: wave W owns j in [32W, 32W+32) of all 3 gates (6 tiles, 24 MFMA,
// 8-h elementwise per step — half of R6's per-wave chain; 2x the waves).
// h exchanged via double-buffered LDS, ONE 2-wave __syncthreads per step.
// XCD swizzle keeps each XCD's gi slice at 3MB (< 4MB L2).
__global__ __launch_bounds__(128, 3) void gru_kernel(
    const float* __restrict__ gi2, const int4v* __restrict__ wfrag,
    const float* __restrict__ b_hh, const float* __restrict__ W1,
    const float* __restrict__ b1, const float* __restrict__ W2,
    const float* __restrict__ b2, const int* __restrict__ dones,
    float* __restrict__ out)
{
    __shared__ __align__(16) unsigned short Hb[2][2][16 * 72];  // 9.2 KB
    __shared__ int sfirst[16];

    const int tid = threadIdx.x;
    const int lane = tid & 63;
    const int W = tid >> 6;          // wave id = j-half owner
    const int li = lane & 15;        // t within group (MFMA col)
    const int q = lane >> 4;         // quad
    const int blk = ((int)blockIdx.x & 7) * 256 + ((int)blockIdx.x >> 3);
    const int T0 = blk * 16;
    const int t = T0 + li;

    // W_hh hi fragments for this wave's 6 tiles: [g][m2][kt]
    bf16x8 whi[3][2][2];
#pragma unroll
    for (int g = 0; g < 3; ++g)
#pragma unroll
        for (int m2 = 0; m2 < 2; ++m2)
#pragma unroll
            for (int kt = 0; kt < 2; ++kt) {
                const int fb = ((4 * g + 2 * W + m2) * 2 + kt);
                frag_cast c; c.i4 = wfrag[fb * 64 + lane];
                whi[g][m2][kt] = c.h8;
            }

    if (tid < 16) {                  // window start: dones[t-19..t-1] only
        const int tt = T0 + tid;
        int lo = tt - (LH - 1); if (lo < 0) lo = 0;
        int ws = lo;
        for (int j = lo; j < tt; ++j)
            ws = (dones[j] != 0) ? (j + 1) : ws;
        sfirst[tid] = ws - (tt - (LH - 1));
    }

    f32x4 bnv[2];                    // n-gate acc init = b_hh_n (this j-half)
#pragma unroll
    for (int m2 = 0; m2 < 2; ++m2)
        bnv[m2] = *(const f32x4*)&b_hh[128 + 32 * W + 16 * m2 + 4 * q];

    __syncthreads();
    const int sfr = sfirst[li];

    const int joff = 32 * W + 4 * q; // this thread's gi column base (+16*m2)
    float h[8];                      // h[j = 32W + 16m2 + 4q + rr]
#pragma unroll
    for (int i = 0; i < 8; ++i) h[i] = 0.f;

    f32x4 accR[2], accZ[2], accN[2], ginv[2];
    f32x4 gvR[2], gvZ[2], gvN[2];

    // ---- s = 0 (h=0: no MFMA), writes buf1 for s=1 ----
    {
        int g = t - (LH - 1); g = g < 0 ? 0 : g;
        const float* gp = gi2 + (size_t)g * G3;
#pragma unroll
        for (int m2 = 0; m2 < 2; ++m2) {
            accR[m2] = *(const f32x4*)(gp + joff + 16 * m2);
            accZ[m2] = *(const f32x4*)(gp + 64 + joff + 16 * m2);
            ginv[m2] = *(const f32x4*)(gp + 128 + joff + 16 * m2);
            accN[m2] = bnv[m2];
        }
        const bool valid = (0 >= sfr);
#pragma unroll
        for (int m2 = 0; m2 < 2; ++m2)
#pragma unroll
            for (int rr = 0; rr < 4; ++rr) {
                const float r  = fast_sigmoid(accR[m2][rr]);
                const float z  = fast_sigmoid(accZ[m2][rr]);
                const float nc = fast_tanh(ginv[m2][rr] + r * accN[m2][rr]);
                h[m2 * 4 + rr] = valid ? fmaf(z, 0.f - nc, nc) : 0.f;
            }
#pragma unroll
        for (int m2 = 0; m2 < 2; ++m2) {
            const unsigned u0 = f2u(h[m2 * 4 + 0]), u1 = f2u(h[m2 * 4 + 1]);
            const unsigned u2 = f2u(h[m2 * 4 + 2]), u3 = f2u(h[m2 * 4 + 3]);
            uint2 ph, pl;
            ph.x = __builtin_amdgcn_perm(u1, u0, 0x07060302u);
            ph.y = __builtin_amdgcn_perm(u3, u2, 0x07060302u);
            const unsigned l0 = f2u(h[m2 * 4 + 0] - u2f(u0 & 0xFFFF0000u));
            const unsigned l1 = f2u(h[m2 * 4 + 1] - u2f(u1 & 0xFFFF0000u));
            const unsigned l2 = f2u(h[m2 * 4 + 2] - u2f(u2 & 0xFFFF0000u));
            const unsigned l3 = f2u(h[m2 * 4 + 3] - u2f(u3 & 0xFFFF0000u));
            pl.x = __builtin_amdgcn_perm(l1, l0, 0x07060302u);
            pl.y = __builtin_amdgcn_perm(l3, l2, 0x07060302u);
            *(uint2*)&Hb[1][0][li * 72 + joff + 16 * m2] = ph;
            *(uint2*)&Hb[1][1][li * 72 + joff + 16 * m2] = pl;
        }
    }
    {   // prefetch gv for s = 1
        int g = t - (LH - 1) + 1; g = g < 0 ? 0 : g;
        const float* gp = gi2 + (size_t)g * G3;
#pragma unroll
        for (int m2 = 0; m2 < 2; ++m2) {
            gvR[m2] = *(const f32x4*)(gp + joff + 16 * m2);
            gvZ[m2] = *(const f32x4*)(gp + 64 + joff + 16 * m2);
            gvN[m2] = *(const f32x4*)(gp + 128 + joff + 16 * m2);
        }
    }
    __syncthreads();

#pragma unroll 2
    for (int s = 1; s < LH; ++s) {
        const int rb = s & 1;        // read buffer; write buffer = 1-rb
        const bf16x8 bh0 = *(const bf16x8*)&Hb[rb][0][li * 72 + 8 * q];
        const bf16x8 bh1 = *(const bf16x8*)&Hb[rb][0][li * 72 + 32 + 8 * q];
        const bf16x8 bl0 = *(const bf16x8*)&Hb[rb][1][li * 72 + 8 * q];
        const bf16x8 bl1 = *(const bf16x8*)&Hb[rb][1][li * 72 + 32 + 8 * q];

#pragma unroll
        for (int m2 = 0; m2 < 2; ++m2) {
            accR[m2] = gvR[m2]; accZ[m2] = gvZ[m2];
            ginv[m2] = gvN[m2]; accN[m2] = bnv[m2];
        }
        {   // prefetch s+1 (hidden under MFMA + elementwise)
            int g = t - (LH - 1) + s + 1;
            g = g < 0 ? 0 : (g > NT - 1 ? NT - 1 : g);
            const float* gp = gi2 + (size_t)g * G3;
#pragma unroll
            for (int m2 = 0; m2 < 2; ++m2) {
                gvR[m2] = *(const f32x4*)(gp + joff + 16 * m2);
                gvZ[m2] = *(const f32x4*)(gp + 64 + joff + 16 * m2);
                gvN[m2] = *(const f32x4*)(gp + 128 + joff + 16 * m2);
            }
        }
#pragma unroll
        for (int g = 0; g < 3; ++g)
#pragma unroll
            for (int m2 = 0; m2 < 2; ++m2) {
                f32x4 a = (g == 0) ? accR[m2] : (g == 1) ? accZ[m2] : accN[m2];
                a = __builtin_amdgcn_mfma_f32_16x16x32_bf16(whi[g][m2][0], bh0, a, 0, 0, 0);
                a = __builtin_amdgcn_mfma_f32_16x16x32_bf16(whi[g][m2][1], bh1, a, 0, 0, 0);
                a = __builtin_amdgcn_mfma_f32_16x16x32_bf16(whi[g][m2][0], bl0, a, 0, 0, 0);
                a = __builtin_amdgcn_mfma_f32_16x16x32_bf16(whi[g][m2][1], bl1, a, 0, 0, 0);
                if (g == 0) accR[m2] = a; else if (g == 1) accZ[m2] = a; else accN[m2] = a;
            }
        const bool valid = (s >= sfr);
#pragma unroll
        for (int m2 = 0; m2 < 2; ++m2)
#pragma unroll
            for (int rr = 0; rr < 4; ++rr) {
                const float r  = fast_sigmoid(accR[m2][rr]);
                const float z  = fast_sigmoid(accZ[m2][rr]);
                const float nc = fast_tanh(ginv[m2][rr] + r * accN[m2][rr]);
                const float hn = fmaf(z, h[m2 * 4 + rr] - nc, nc);
                h[m2 * 4 + rr] = valid ? hn : h[m2 * 4 + rr];
            }
#pragma unroll
        for (int m2 = 0; m2 < 2; ++m2) {
            const unsigned u0 = f2u(h[m2 * 4 + 0]), u1 = f2u(h[m2 * 4 + 1]);
            const unsigned u2 = f2u(h[m2 * 4 + 2]), u3 = f2u(h[m2 * 4 + 3]);
            uint2 ph, pl;
            ph.x = __builtin_amdgcn_perm(u1, u0, 0x07060302u);
            ph.y = __builtin_amdgcn_perm(u3, u2, 0x07060302u);
            const unsigned l0 = f2u(h[m2 * 4 + 0] - u2f(u0 & 0xFFFF0000u));
            const unsigned l1 = f2u(h[m2 * 4 + 1] - u2f(u1 & 0xFFFF0000u));
            const unsigned l2 = f2u(h[m2 * 4 + 2] - u2f(u2 & 0xFFFF0000u));
            const unsigned l3 = f2u(h[m2 * 4 + 3] - u2f(u3 & 0xFFFF0000u));
            pl.x = __builtin_amdgcn_perm(l1, l0, 0x07060302u);
            pl.y = __builtin_amdgcn_perm(l3, l2, 0x07060302u);
            *(uint2*)&Hb[1 - rb][0][li * 72 + joff + 16 * m2] = ph;
            *(uint2*)&Hb[1 - rb][1][li * 72 + joff + 16 * m2] = pl;
        }
        __syncthreads();             // writes visible; WAR safe via dbl-buffer
    }

    // ---- MLP (block-level, 16 t) ----
    float* const Hf  = (float*)&Hb[0][0][0];     // [t][k] stride 68 (4352 B)
    float* const Hid = Hf + 16 * 68;             // [t][m] stride 68 (fits 9.2KB)
#pragma unroll
    for (int m2 = 0; m2 < 2; ++m2) {
        float4 st;
        st.x = h[m2 * 4 + 0]; st.y = h[m2 * 4 + 1];
        st.z = h[m2 * 4 + 2]; st.w = h[m2 * 4 + 3];
        *(float4*)&Hf[li * 68 + joff + 16 * m2] = st;
    }
    __syncthreads();
    // MLP1: lane = m, wave W handles t in [8W, 8W+8)
    {
        float hid[8];
#pragma unroll
        for (int i = 0; i < 8; ++i) hid[i] = 0.f;
        for (int k4 = 0; k4 < 16; ++k4) {
            const float4 wv = *(const float4*)&W1[lane * HH + 4 * k4];
#pragma unroll
            for (int tt = 0; tt < 8; ++tt) {
                const float4 hv = *(const float4*)&Hf[(8 * W + tt) * 68 + 4 * k4];
                hid[tt] += hv.x * wv.x + hv.y * wv.y + hv.z * wv.z + hv.w * wv.w;
            }
        }
        const float bb = b1[lane];
#pragma unroll
        for (int tt = 0; tt < 8; ++tt)
            Hid[(8 * W + tt) * 68 + lane] = fmaxf(hid[tt] + bb, 0.f);
    }
    __syncthreads();
    // MLP2: wave 0, thread (li -> t, q -> c)
    if (tid < 64) {
        float o2 = b2[q];
        for (int m4 = 0; m4 < 16; ++m4) {
            const float4 hv = *(const float4*)&Hid[li * 68 + 4 * m4];
            const float4 wv = *(const float4*)&W2[q * HH + 4 * m4];
            o2 += hv.x * wv.x + hv.y * wv.y + hv.z * wv.z + hv.w * wv.w;
        }
        out[(size_t)t * 4 + q] = o2;             // 256B contiguous per wave
    }
}

extern "C" void kernel_launch(void* const* d_in, const int* in_sizes, int n_in,
                              void* d_out, int out_size, void* d_ws, size_t ws_size,
                              hipStream_t stream) {
    const float* emb  = (const float*)d_in[0];
    const float* W_ih = (const float*)d_in[1];
    const float* W_hh = (const float*)d_in[2];
    const float* b_ih = (const float*)d_in[3];
    const float* b_hh = (const float*)d_in[4];
    const float* W1   = (const float*)d_in[5];
    const float* b1   = (const float*)d_in[6];
    const float* W2   = (const float*)d_in[7];
    const float* b2   = (const float*)d_in[8];
    const int*   dn   = (const int*)d_in[9];

    float* gi2   = (float*)d_ws;                                 // 25.2 MB
    int4v* wfrag = (int4v*)((char*)d_ws + (size_t)NT * G3 * 4);  // +24 KB
    float* o     = (float*)d_out;

    prep_kernel<<<NT / 32, 192, 0, stream>>>(emb, W_ih, b_ih, b_hh, W_hh, gi2, wfrag);
    gru_kernel<<<NT / 16, 128, 0, stream>>>(gi2, wfrag, b_hh, W1, b1, W2, b2, dn, o);
}

// Round 8
// 178.960 us; speedup vs baseline: 1.0264x; 1.0264x over previous
//
#include <hip/hip_runtime.h>

#define NT 32768
#define DI 36
#define HH 64
#define G3 192
#define LH 20

#define NLOG2E -1.4426950408889634f   // r/z pre-scale: sigmoid(x)=rcp(1+exp2(-x*log2e))
#define TLOG2E 2.8853900817779268f    // n pre-scale: tanh(x)=1-2*rcp(1+exp2(2x*log2e))

typedef __attribute__((ext_vector_type(8))) short bf16x8;
typedef __attribute__((ext_vector_type(4))) float f32x4;
typedef __attribute__((ext_vector_type(4))) int int4v;
union frag_cast { int4v i4; bf16x8 h8; };

__device__ __forceinline__ unsigned f2u(float f) { union { float f; unsigned u; } x; x.f = f; return x.u; }
__device__ __forceinline__ float u2f(unsigned u) { union { float f; unsigned u; } x; x.u = u; return x.f; }
__device__ __forceinline__ unsigned short f2bf_rne(float f) {
    union { float f; unsigned u; } x; x.f = f;
    unsigned r = x.u + 0x7FFFu + ((x.u >> 16) & 1u);
    return (unsigned short)(r >> 16);
}

// Kernel 1: gi2[t][j] = (emb[t,:].W_ih[j,:] + b_ih[j] + (j<128 ? b_hh[j] : 0)) * scale(j)
// scale = -log2e for r/z rows, 2*log2e for n rows (folds the transcendental
// argument scaling out of the gru inner loop). Blocks 0..23 emit W_hh
// hi-fragments with the same row scaling.
// Fragment convention (verified R3): A[m=16mt+(l&15)][k=32kt+8(l>>4)+jj].
__global__ __launch_bounds__(192, 2) void prep_kernel(
    const float* __restrict__ emb, const float* __restrict__ W_ih,
    const float* __restrict__ b_ih, const float* __restrict__ b_hh,
    const float* __restrict__ W_hh,
    float* __restrict__ gi2, int4v* __restrict__ wfrag)
{
    __shared__ float L[DI * 193 + DI * 36];
    float* const Wt = L;              // [k][j]  stride 193
    float* const Et = L + DI * 193;   // [k][ti] stride 36
    const int tid = threadIdx.x;
    const int t0 = blockIdx.x * 32;

    for (int i = tid; i < G3 * DI; i += 192)
        Wt[(i % DI) * 193 + i / DI] = W_ih[i];
    for (int i = tid; i < 32 * DI; i += 192)
        Et[(i % DI) * 36 + i / DI] = emb[(size_t)t0 * DI + i];
    __syncthreads();

    float acc[32];
#pragma unroll
    for (int i = 0; i < 32; ++i) acc[i] = 0.f;
    for (int k = 0; k < DI; ++k) {
        const float w = Wt[k * 193 + tid];
#pragma unroll
        for (int i4 = 0; i4 < 8; ++i4) {
            const float4 e = *(const float4*)&Et[k * 36 + i4 * 4];  // broadcast
            acc[i4 * 4 + 0] = fmaf(e.x, w, acc[i4 * 4 + 0]);
            acc[i4 * 4 + 1] = fmaf(e.y, w, acc[i4 * 4 + 1]);
            acc[i4 * 4 + 2] = fmaf(e.z, w, acc[i4 * 4 + 2]);
            acc[i4 * 4 + 3] = fmaf(e.w, w, acc[i4 * 4 + 3]);
        }
    }
    const float bias = b_ih[tid] + (tid < 128 ? b_hh[tid] : 0.f);
    const float sc = (tid < 128) ? NLOG2E : TLOG2E;
#pragma unroll
    for (int i = 0; i < 32; ++i)
        gi2[(size_t)(t0 + i) * G3 + tid] = (acc[i] + bias) * sc;  // coalesced

    if (blockIdx.x < 24 && tid < 64) {
        const int mt = (int)blockIdx.x >> 1, kt = (int)blockIdx.x & 1;
        const int m = mt * 16 + (tid & 15);
        const int k0 = kt * 32 + (tid >> 4) * 8;
        const float scw = (mt < 8) ? NLOG2E : TLOG2E;
        unsigned short e[8];
#pragma unroll
        for (int jj = 0; jj < 8; ++jj)
            e[jj] = f2bf_rne(W_hh[m * HH + k0 + jj] * scw);
        int4v p;
        p.x = e[0] | ((unsigned)e[1] << 16); p.y = e[2] | ((unsigned)e[3] << 16);
        p.z = e[4] | ((unsigned)e[5] << 16); p.w = e[6] | ((unsigned)e[7] << 16);
        wfrag[(int)blockIdx.x * 64 + tid] = p;
    }
}

// Main kernel: 2048 blocks x 256 thr (4 waves) = one 16-t group per block.
// 4-way j-SPLIT: wave W owns j in [16W,16W+16) of all 3 gates (6 frags,
// 12 MFMA, 4-h elementwise per step). 8192 waves total (8/SIMD offered,
// ~5 resident at ~100 VGPR). h exchanged via double-buffered LDS, one
// 4-wave __syncthreads per step. XCD swizzle keeps gi slice L2-resident.
__global__ __launch_bounds__(256, 5) void gru_kernel(
    const float* __restrict__ gi2, const int4v* __restrict__ wfrag,
    const float* __restrict__ b_hh, const float* __restrict__ W1,
    const float* __restrict__ b1, const float* __restrict__ W2,
    const float* __restrict__ b2, const int* __restrict__ dones,
    float* __restrict__ out)
{
    __shared__ __align__(16) unsigned short Hb[2][2][16 * 72];  // 9.2 KB
    __shared__ int sfirst[16];

    const int tid = threadIdx.x;
    const int lane = tid & 63;
    const int W = tid >> 6;          // wave id = j-quarter owner
    const int li = lane & 15;        // t within group (MFMA col)
    const int q = lane >> 4;         // quad
    const int blk = ((int)blockIdx.x & 7) * 256 + ((int)blockIdx.x >> 3);
    const int T0 = blk * 16;
    const int t = T0 + li;

    // W_hh hi fragments for this wave's 3 gate-tiles (mt = 4g + W)
    bf16x8 whi[3][2];
#pragma unroll
    for (int g = 0; g < 3; ++g)
#pragma unroll
        for (int kt = 0; kt < 2; ++kt) {
            frag_cast c; c.i4 = wfrag[((4 * g + W) * 2 + kt) * 64 + lane];
            whi[g][kt] = c.h8;
        }

    if (tid < 16) {                  // window start: dones[t-19..t-1] only
        const int tt = T0 + tid;
        int lo = tt - (LH - 1); if (lo < 0) lo = 0;
        int ws = lo;
        for (int j = lo; j < tt; ++j)
            ws = (dones[j] != 0) ? (j + 1) : ws;
        sfirst[tid] = ws - (tt - (LH - 1));
    }

    const int joff = 16 * W + 4 * q; // this thread's j' base within each gate
    f32x4 bnv;                       // n-gate acc init = 2*log2e * b_hh_n
    {
        const f32x4 b = *(const f32x4*)&b_hh[128 + joff];
        bnv[0] = b[0] * TLOG2E; bnv[1] = b[1] * TLOG2E;
        bnv[2] = b[2] * TLOG2E; bnv[3] = b[3] * TLOG2E;
    }

    __syncthreads();
    const int sfr = sfirst[li];

    float h[4] = {0.f, 0.f, 0.f, 0.f};
    f32x4 accR, accZ, accN, ginv;
    f32x4 gvR, gvZ, gvN;

    // ---- s = 0 (h=0: no MFMA), writes buf1 for s=1 ----
    {
        int g = t - (LH - 1); g = g < 0 ? 0 : g;
        const float* gp = gi2 + (size_t)g * G3;
        accR = *(const f32x4*)(gp + joff);
        accZ = *(const f32x4*)(gp + 64 + joff);
        ginv = *(const f32x4*)(gp + 128 + joff);
        accN = bnv;
        const bool valid = (0 >= sfr);
#pragma unroll
        for (int rr = 0; rr < 4; ++rr) {
            const float r  = __builtin_amdgcn_rcpf(1.f + __builtin_amdgcn_exp2f(accR[rr]));
            const float z  = __builtin_amdgcn_rcpf(1.f + __builtin_amdgcn_exp2f(accZ[rr]));
            const float nc = 1.f - 2.f * __builtin_amdgcn_rcpf(1.f + __builtin_amdgcn_exp2f(ginv[rr] + r * accN[rr]));
            h[rr] = valid ? fmaf(z, 0.f - nc, nc) : 0.f;
        }
        {
            const unsigned u0 = f2u(h[0]), u1 = f2u(h[1]);
            const unsigned u2 = f2u(h[2]), u3 = f2u(h[3]);
            uint2 ph, pl;
            ph.x = __builtin_amdgcn_perm(u1, u0, 0x07060302u);
            ph.y = __builtin_amdgcn_perm(u3, u2, 0x07060302u);
            const unsigned l0 = f2u(h[0] - u2f(u0 & 0xFFFF0000u));
            const unsigned l1 = f2u(h[1] - u2f(u1 & 0xFFFF0000u));
            const unsigned l2 = f2u(h[2] - u2f(u2 & 0xFFFF0000u));
            const unsigned l3 = f2u(h[3] - u2f(u3 & 0xFFFF0000u));
            pl.x = __builtin_amdgcn_perm(l1, l0, 0x07060302u);
            pl.y = __builtin_amdgcn_perm(l3, l2, 0x07060302u);
            *(uint2*)&Hb[1][0][li * 72 + joff] = ph;
            *(uint2*)&Hb[1][1][li * 72 + joff] = pl;
        }
    }
    {   // prefetch gv for s = 1
        int g = t - (LH - 1) + 1; g = g < 0 ? 0 : g;
        const float* gp = gi2 + (size_t)g * G3;
        gvR = *(const f32x4*)(gp + joff);
        gvZ = *(const f32x4*)(gp + 64 + joff);
        gvN = *(const f32x4*)(gp + 128 + joff);
    }
    __syncthreads();

#pragma unroll 2
    for (int s = 1; s < LH; ++s) {
        const int rb = s & 1;        // read buffer; write buffer = 1-rb
        const bf16x8 bh0 = *(const bf16x8*)&Hb[rb][0][li * 72 + 8 * q];
        const bf16x8 bh1 = *(const bf16x8*)&Hb[rb][0][li * 72 + 32 + 8 * q];
        const bf16x8 bl0 = *(const bf16x8*)&Hb[rb][1][li * 72 + 8 * q];
        const bf16x8 bl1 = *(const bf16x8*)&Hb[rb][1][li * 72 + 32 + 8 * q];

        accR = gvR; accZ = gvZ; ginv = gvN; accN = bnv;
        {   // prefetch s+1 (hidden under MFMA + elementwise)
            int g = t - (LH - 1) + s + 1;
            g = g < 0 ? 0 : (g > NT - 1 ? NT - 1 : g);
            const float* gp = gi2 + (size_t)g * G3;
            gvR = *(const f32x4*)(gp + joff);
            gvZ = *(const f32x4*)(gp + 64 + joff);
            gvN = *(const f32x4*)(gp + 128 + joff);
        }
#pragma unroll
        for (int g = 0; g < 3; ++g) {
            f32x4 a = (g == 0) ? accR : (g == 1) ? accZ : accN;
            a = __builtin_amdgcn_mfma_f32_16x16x32_bf16(whi[g][0], bh0, a, 0, 0, 0);
            a = __builtin_amdgcn_mfma_f32_16x16x32_bf16(whi[g][1], bh1, a, 0, 0, 0);
            a = __builtin_amdgcn_mfma_f32_16x16x32_bf16(whi[g][0], bl0, a, 0, 0, 0);
            a = __builtin_amdgcn_mfma_f32_16x16x32_bf16(whi[g][1], bl1, a, 0, 0, 0);
            if (g == 0) accR = a; else if (g == 1) accZ = a; else accN = a;
        }
        const bool valid = (s >= sfr);
#pragma unroll
        for (int rr = 0; rr < 4; ++rr) {
            const float r  = __builtin_amdgcn_rcpf(1.f + __builtin_amdgcn_exp2f(accR[rr]));
            const float z  = __builtin_amdgcn_rcpf(1.f + __builtin_amdgcn_exp2f(accZ[rr]));
            const float nc = 1.f - 2.f * __builtin_amdgcn_rcpf(1.f + __builtin_amdgcn_exp2f(ginv[rr] + r * accN[rr]));
            const float hn = fmaf(z, h[rr] - nc, nc);
            h[rr] = valid ? hn : h[rr];
        }
        {
            const unsigned u0 = f2u(h[0]), u1 = f2u(h[1]);
            const unsigned u2 = f2u(h[2]), u3 = f2u(h[3]);
            uint2 ph, pl;
            ph.x = __builtin_amdgcn_perm(u1, u0, 0x07060302u);
            ph.y = __builtin_amdgcn_perm(u3, u2, 0x07060302u);
            const unsigned l0 = f2u(h[0] - u2f(u0 & 0xFFFF0000u));
            const unsigned l1 = f2u(h[1] - u2f(u1 & 0xFFFF0000u));
            const unsigned l2 = f2u(h[2] - u2f(u2 & 0xFFFF0000u));
            const unsigned l3 = f2u(h[3] - u2f(u3 & 0xFFFF0000u));
            pl.x = __builtin_amdgcn_perm(l1, l0, 0x07060302u);
            pl.y = __builtin_amdgcn_perm(l3, l2, 0x07060302u);
            *(uint2*)&Hb[1 - rb][0][li * 72 + joff] = ph;
            *(uint2*)&Hb[1 - rb][1][li * 72 + joff] = pl;
        }
        __syncthreads();             // writes visible; WAR safe via dbl-buffer
    }

    // ---- MLP (block-level, 16 t) ----
    float* const Hf  = (float*)&Hb[0][0][0];     // [t][k] stride 68
    float* const Hid = Hf + 16 * 68;             // [t][m] stride 68 (8.7KB tot)
    {
        float4 st; st.x = h[0]; st.y = h[1]; st.z = h[2]; st.w = h[3];
        *(float4*)&Hf[li * 68 + joff] = st;
    }
    __syncthreads();
    // MLP1: lane = m, wave W handles t in [4W, 4W+4)
    {
        float hid[4] = {0.f, 0.f, 0.f, 0.f};
        for (int k4 = 0; k4 < 16; ++k4) {
            const float4 wv = *(const float4*)&W1[lane * HH + 4 * k4];
#pragma unroll
            for (int tt = 0; tt < 4; ++tt) {
                const float4 hv = *(const float4*)&Hf[(4 * W + tt) * 68 + 4 * k4];
                hid[tt] += hv.x * wv.x + hv.y * wv.y + hv.z * wv.z + hv.w * wv.w;
            }
        }
        const float bb = b1[lane];
#pragma unroll
        for (int tt = 0; tt < 4; ++tt)
            Hid[(4 * W + tt) * 68 + lane] = fmaxf(hid[tt] + bb, 0.f);
    }
    __syncthreads();
    // MLP2: wave 0, thread (tid>>2 -> t, tid&3 -> c)
    if (tid < 64) {
        const int tt = tid >> 2, c = tid & 3;
        float o2 = b2[c];
        for (int m4 = 0; m4 < 16; ++m4) {
            const float4 hv = *(const float4*)&Hid[tt * 68 + 4 * m4];
            const float4 wv = *(const float4*)&W2[c * HH + 4 * m4];
            o2 += hv.x * wv.x + hv.y * wv.y + hv.z * wv.z + hv.w * wv.w;
        }
        out[(size_t)(T0 + tt) * 4 + c] = o2;     // 256B contiguous
    }
}

extern "C" void kernel_launch(void* const* d_in, const int* in_sizes, int n_in,
                              void* d_out, int out_size, void* d_ws, size_t ws_size,
                              hipStream_t stream) {
    const float* emb  = (const float*)d_in[0];
    const float* W_ih = (const float*)d_in[1];
    const float* W_hh = (const float*)d_in[2];
    const float* b_ih = (const float*)d_in[3];
    const float* b_hh = (const float*)d_in[4];
    const float* W1   = (const float*)d_in[5];
    const float* b1   = (const float*)d_in[6];
    const float* W2   = (const float*)d_in[7];
    const float* b2   = (const float*)d_in[8];
    const int*   dn   = (const int*)d_in[9];

    float* gi2   = (float*)d_ws;                                 // 25.2 MB
    int4v* wfrag = (int4v*)((char*)d_ws + (size_t)NT * G3 * 4);  // +24 KB
    float* o     = (float*)d_out;

    prep_kernel<<<NT / 32, 192, 0, stream>>>(emb, W_ih, b_ih, b_hh, W_hh, gi2, wfrag);
    gru_kernel<<<NT / 16, 256, 0, stream>>>(gi2, wfrag, b_hh, W1, b1, W2, b2, dn, o);
}

// Round 9
// 152.724 us; speedup vs baseline: 1.2028x; 1.1718x over previous
//
#include <hip/hip_runtime.h>

#define NT 32768
#define DI 36
#define HH 64
#define G3 192
#define LH 20
#define SGS 196            // padded LDS row stride for gi slice (16B-aligned)

#define NLOG2E -1.4426950408889634f   // r/z pre-scale: sigmoid(x)=rcp(1+exp2(-x*log2e))
#define TLOG2E 2.8853900817779268f    // n pre-scale: tanh(x)=1-2*rcp(1+exp2(2x*log2e))

typedef __attribute__((ext_vector_type(8))) short bf16x8;
typedef __attribute__((ext_vector_type(4))) float f32x4;
typedef __attribute__((ext_vector_type(4))) int int4v;
union frag_cast { int4v i4; bf16x8 h8; };

__device__ __forceinline__ unsigned f2u(float f) { union { float f; unsigned u; } x; x.f = f; return x.u; }
__device__ __forceinline__ float u2f(unsigned u) { union { float f; unsigned u; } x; x.u = u; return x.f; }
__device__ __forceinline__ unsigned short f2bf_rne(float f) {
    union { float f; unsigned u; } x; x.f = f;
    unsigned r = x.u + 0x7FFFu + ((x.u >> 16) & 1u);
    return (unsigned short)(r >> 16);
}

// Kernel 1: gi2[t][j] = (emb[t,:].W_ih[j,:] + b_ih[j] + (j<128 ? b_hh[j] : 0)) * scale(j)
// scale = -log2e (r/z) or 2*log2e (n): folds transcendental arg scaling out of
// the gru loop. Blocks 0..23 emit W_hh hi-fragments with the same row scaling.
// Fragment convention (verified R3): A[m=16mt+(l&15)][k=32kt+8(l>>4)+jj].
__global__ __launch_bounds__(192, 2) void prep_kernel(
    const float* __restrict__ emb, const float* __restrict__ W_ih,
    const float* __restrict__ b_ih, const float* __restrict__ b_hh,
    const float* __restrict__ W_hh,
    float* __restrict__ gi2, int4v* __restrict__ wfrag)
{
    __shared__ float L[DI * 193 + DI * 36];
    float* const Wt = L;              // [k][j]  stride 193
    float* const Et = L + DI * 193;   // [k][ti] stride 36
    const int tid = threadIdx.x;
    const int t0 = blockIdx.x * 32;

    for (int i = tid; i < G3 * DI; i += 192)
        Wt[(i % DI) * 193 + i / DI] = W_ih[i];
    for (int i = tid; i < 32 * DI; i += 192)
        Et[(i % DI) * 36 + i / DI] = emb[(size_t)t0 * DI + i];
    __syncthreads();

    float acc[32];
#pragma unroll
    for (int i = 0; i < 32; ++i) acc[i] = 0.f;
    for (int k = 0; k < DI; ++k) {
        const float w = Wt[k * 193 + tid];
#pragma unroll
        for (int i4 = 0; i4 < 8; ++i4) {
            const float4 e = *(const float4*)&Et[k * 36 + i4 * 4];  // broadcast
            acc[i4 * 4 + 0] = fmaf(e.x, w, acc[i4 * 4 + 0]);
            acc[i4 * 4 + 1] = fmaf(e.y, w, acc[i4 * 4 + 1]);
            acc[i4 * 4 + 2] = fmaf(e.z, w, acc[i4 * 4 + 2]);
            acc[i4 * 4 + 3] = fmaf(e.w, w, acc[i4 * 4 + 3]);
        }
    }
    const float bias = b_ih[tid] + (tid < 128 ? b_hh[tid] : 0.f);
    const float sc = (tid < 128) ? NLOG2E : TLOG2E;
#pragma unroll
    for (int i = 0; i < 32; ++i)
        gi2[(size_t)(t0 + i) * G3 + tid] = (acc[i] + bias) * sc;  // coalesced

    if (blockIdx.x < 24 && tid < 64) {
        const int mt = (int)blockIdx.x >> 1, kt = (int)blockIdx.x & 1;
        const int m = mt * 16 + (tid & 15);
        const int k0 = kt * 32 + (tid >> 4) * 8;
        const float scw = (mt < 8) ? NLOG2E : TLOG2E;
        unsigned short e[8];
#pragma unroll
        for (int jj = 0; jj < 8; ++jj)
            e[jj] = f2bf_rne(W_hh[m * HH + k0 + jj] * scw);
        int4v p;
        p.x = e[0] | ((unsigned)e[1] << 16); p.y = e[2] | ((unsigned)e[3] << 16);
        p.z = e[4] | ((unsigned)e[5] << 16); p.w = e[6] | ((unsigned)e[7] << 16);
        wfrag[(int)blockIdx.x * 64 + tid] = p;
    }
}

// Main kernel: 2048 blocks x 256 thr (4 waves) = one 16-t group per block.
// NEW vs R8: the block's full gi window (35 rows = t in [T0-19, T0+15]) is
// staged to LDS once, so the 20-step loop touches ONLY LDS — the per-step
// __syncthreads no longer drains in-flight VMEM (the R8 critical-path killer).
// 4-way j-split: wave W owns j in [16W,16W+16) of all 3 gates (12 MFMA/step).
__global__ __launch_bounds__(256, 4) void gru_kernel(
    const float* __restrict__ gi2, const int4v* __restrict__ wfrag,
    const float* __restrict__ b_hh, const float* __restrict__ W1,
    const float* __restrict__ b1, const float* __restrict__ W2,
    const float* __restrict__ b2, const int* __restrict__ dones,
    float* __restrict__ out)
{
    __shared__ __align__(16) float Sg[35 * SGS];                // 27.4 KB gi slice
    __shared__ __align__(16) unsigned short Hb[2][2][16 * 72];  // 9.2 KB
    __shared__ int sfirst[16];

    const int tid = threadIdx.x;
    const int lane = tid & 63;
    const int W = tid >> 6;          // wave id = j-quarter owner
    const int li = lane & 15;        // t within group (MFMA col)
    const int q = lane >> 4;         // quad
    const int blk = ((int)blockIdx.x & 7) * 256 + ((int)blockIdx.x >> 3);
    const int T0 = blk * 16;
    const int t = T0 + li;

    // stage gi window: rows r=0..34 <-> t = T0-19+r (clamped; invalid masked by sfr)
    for (int i = tid; i < 35 * 48; i += 256) {
        const int r = i / 48, c = (i % 48) * 4;
        int tt = T0 - (LH - 1) + r;
        tt = tt < 0 ? 0 : tt;
        *(float4*)&Sg[r * SGS + c] = *(const float4*)&gi2[(size_t)tt * G3 + c];
    }

    // W_hh hi fragments for this wave's 3 gate-tiles (mt = 4g + W)
    bf16x8 whi[3][2];
#pragma unroll
    for (int g = 0; g < 3; ++g)
#pragma unroll
        for (int kt = 0; kt < 2; ++kt) {
            frag_cast c; c.i4 = wfrag[((4 * g + W) * 2 + kt) * 64 + lane];
            whi[g][kt] = c.h8;
        }

    if (tid < 16) {                  // window start: dones[t-19..t-1] only
        const int tt = T0 + tid;
        int lo = tt - (LH - 1); if (lo < 0) lo = 0;
        int ws = lo;
        for (int j = lo; j < tt; ++j)
            ws = (dones[j] != 0) ? (j + 1) : ws;
        sfirst[tid] = ws - (tt - (LH - 1));
    }

    const int joff = 16 * W + 4 * q; // this thread's j' base within each gate
    f32x4 bnv;                       // n-gate acc init = 2*log2e * b_hh_n
    {
        const f32x4 b = *(const f32x4*)&b_hh[128 + joff];
        bnv[0] = b[0] * TLOG2E; bnv[1] = b[1] * TLOG2E;
        bnv[2] = b[2] * TLOG2E; bnv[3] = b[3] * TLOG2E;
    }

    __syncthreads();
    const int sfr = sfirst[li];

    float h[4] = {0.f, 0.f, 0.f, 0.f};
    f32x4 accR, accZ, accN, ginv;

    // ---- s = 0 (h=0: no MFMA), writes buf1 for s=1 ----
    {
        const float* gp = Sg + li * SGS;         // row li = t-19+0... wait r = li+s
        accR = *(const f32x4*)(gp + joff);
        accZ = *(const f32x4*)(gp + 64 + joff);
        ginv = *(const f32x4*)(gp + 128 + joff);
        accN = bnv;
        const bool valid = (0 >= sfr);
#pragma unroll
        for (int rr = 0; rr < 4; ++rr) {
            const float r  = __builtin_amdgcn_rcpf(1.f + __builtin_amdgcn_exp2f(accR[rr]));
            const float z  = __builtin_amdgcn_rcpf(1.f + __builtin_amdgcn_exp2f(accZ[rr]));
            const float nc = 1.f - 2.f * __builtin_amdgcn_rcpf(1.f + __builtin_amdgcn_exp2f(ginv[rr] + r * accN[rr]));
            h[rr] = valid ? fmaf(z, 0.f - nc, nc) : 0.f;
        }
        {
            const unsigned u0 = f2u(h[0]), u1 = f2u(h[1]);
            const unsigned u2 = f2u(h[2]), u3 = f2u(h[3]);
            uint2 ph, pl;
            ph.x = __builtin_amdgcn_perm(u1, u0, 0x07060302u);
            ph.y = __builtin_amdgcn_perm(u3, u2, 0x07060302u);
            const unsigned l0 = f2u(h[0] - u2f(u0 & 0xFFFF0000u));
            const unsigned l1 = f2u(h[1] - u2f(u1 & 0xFFFF0000u));
            const unsigned l2 = f2u(h[2] - u2f(u2 & 0xFFFF0000u));
            const unsigned l3 = f2u(h[3] - u2f(u3 & 0xFFFF0000u));
            pl.x = __builtin_amdgcn_perm(l1, l0, 0x07060302u);
            pl.y = __builtin_amdgcn_perm(l3, l2, 0x07060302u);
            *(uint2*)&Hb[1][0][li * 72 + joff] = ph;
            *(uint2*)&Hb[1][1][li * 72 + joff] = pl;
        }
    }
    __syncthreads();

#pragma unroll 2
    for (int s = 1; s < LH; ++s) {
        const int rb = s & 1;        // read buffer; write buffer = 1-rb
        const bf16x8 bh0 = *(const bf16x8*)&Hb[rb][0][li * 72 + 8 * q];
        const bf16x8 bh1 = *(const bf16x8*)&Hb[rb][0][li * 72 + 32 + 8 * q];
        const bf16x8 bl0 = *(const bf16x8*)&Hb[rb][1][li * 72 + 8 * q];
        const bf16x8 bl1 = *(const bf16x8*)&Hb[rb][1][li * 72 + 32 + 8 * q];

        // gi from the LDS slice: row = li + s (in [0,34])
        const float* gp = Sg + (li + s) * SGS;
        accR = *(const f32x4*)(gp + joff);
        accZ = *(const f32x4*)(gp + 64 + joff);
        ginv = *(const f32x4*)(gp + 128 + joff);
        accN = bnv;

#pragma unroll
        for (int g = 0; g < 3; ++g) {
            f32x4 a = (g == 0) ? accR : (g == 1) ? accZ : accN;
            a = __builtin_amdgcn_mfma_f32_16x16x32_bf16(whi[g][0], bh0, a, 0, 0, 0);
            a = __builtin_amdgcn_mfma_f32_16x16x32_bf16(whi[g][1], bh1, a, 0, 0, 0);
            a = __builtin_amdgcn_mfma_f32_16x16x32_bf16(whi[g][0], bl0, a, 0, 0, 0);
            a = __builtin_amdgcn_mfma_f32_16x16x32_bf16(whi[g][1], bl1, a, 0, 0, 0);
            if (g == 0) accR = a; else if (g == 1) accZ = a; else accN = a;
        }
        const bool valid = (s >= sfr);
#pragma unroll
        for (int rr = 0; rr < 4; ++rr) {
            const float r  = __builtin_amdgcn_rcpf(1.f + __builtin_amdgcn_exp2f(accR[rr]));
            const float z  = __builtin_amdgcn_rcpf(1.f + __builtin_amdgcn_exp2f(accZ[rr]));
            const float nc = 1.f - 2.f * __builtin_amdgcn_rcpf(1.f + __builtin_amdgcn_exp2f(ginv[rr] + r * accN[rr]));
            const float hn = fmaf(z, h[rr] - nc, nc);
            h[rr] = valid ? hn : h[rr];
        }
        {
            const unsigned u0 = f2u(h[0]), u1 = f2u(h[1]);
            const unsigned u2 = f2u(h[2]), u3 = f2u(h[3]);
            uint2 ph, pl;
            ph.x = __builtin_amdgcn_perm(u1, u0, 0x07060302u);
            ph.y = __builtin_amdgcn_perm(u3, u2, 0x07060302u);
            const unsigned l0 = f2u(h[0] - u2f(u0 & 0xFFFF0000u));
            const unsigned l1 = f2u(h[1] - u2f(u1 & 0xFFFF0000u));
            const unsigned l2 = f2u(h[2] - u2f(u2 & 0xFFFF0000u));
            const unsigned l3 = f2u(h[3] - u2f(u3 & 0xFFFF0000u));
            pl.x = __builtin_amdgcn_perm(l1, l0, 0x07060302u);
            pl.y = __builtin_amdgcn_perm(l3, l2, 0x07060302u);
            *(uint2*)&Hb[1 - rb][0][li * 72 + joff] = ph;
            *(uint2*)&Hb[1 - rb][1][li * 72 + joff] = pl;
        }
        __syncthreads();             // LDS-only drain now (cheap)
    }

    // ---- MLP (block-level, 16 t); reuse Sg as scratch ----
    float* const Hf  = Sg;                       // [t][k] stride 68
    float* const Hid = Sg + 16 * 68;             // [t][m] stride 68
    {
        float4 st; st.x = h[0]; st.y = h[1]; st.z = h[2]; st.w = h[3];
        *(float4*)&Hf[li * 68 + joff] = st;
    }
    __syncthreads();
    // MLP1: lane = m, wave W handles t in [4W, 4W+4)
    {
        float hid[4] = {0.f, 0.f, 0.f, 0.f};
        for (int k4 = 0; k4 < 16; ++k4) {
            const float4 wv = *(const float4*)&W1[lane * HH + 4 * k4];
#pragma unroll
            for (int tt = 0; tt < 4; ++tt) {
                const float4 hv = *(const float4*)&Hf[(4 * W + tt) * 68 + 4 * k4];
                hid[tt] += hv.x * wv.x + hv.y * wv.y + hv.z * wv.z + hv.w * wv.w;
            }
        }
        const float bb = b1[lane];
#pragma unroll
        for (int tt = 0; tt < 4; ++tt)
            Hid[(4 * W + tt) * 68 + lane] = fmaxf(hid[tt] + bb, 0.f);
    }
    __syncthreads();
    // MLP2: wave 0, thread (tid>>2 -> t, tid&3 -> c)
    if (tid < 64) {
        const int tt = tid >> 2, c = tid & 3;
        float o2 = b2[c];
        for (int m4 = 0; m4 < 16; ++m4) {
            const float4 hv = *(const float4*)&Hid[tt * 68 + 4 * m4];
            const float4 wv = *(const float4*)&W2[c * HH + 4 * m4];
            o2 += hv.x * wv.x + hv.y * wv.y + hv.z * wv.z + hv.w * wv.w;
        }
        out[(size_t)(T0 + tt) * 4 + c] = o2;     // 256B contiguous
    }
}

extern "C" void kernel_launch(void* const* d_in, const int* in_sizes, int n_in,
                              void* d_out, int out_size, void* d_ws, size_t ws_size,
                              hipStream_t stream) {
    const float* emb  = (const float*)d_in[0];
    const float* W_ih = (const float*)d_in[1];
    const float* W_hh = (const float*)d_in[2];
    const float* b_ih = (const float*)d_in[3];
    const float* b_hh = (const float*)d_in[4];
    const float* W1   = (const float*)d_in[5];
    const float* b1   = (const float*)d_in[6];
    const float* W2   = (const float*)d_in[7];
    const float* b2   = (const float*)d_in[8];
    const int*   dn   = (const int*)d_in[9];

    float* gi2   = (float*)d_ws;                                 // 25.2 MB
    int4v* wfrag = (int4v*)((char*)d_ws + (size_t)NT * G3 * 4);  // +24 KB
    float* o     = (float*)d_out;

    prep_kernel<<<NT / 32, 192, 0, stream>>>(emb, W_ih, b_ih, b_hh, W_hh, gi2, wfrag);
    gru_kernel<<<NT / 16, 256, 0, stream>>>(gi2, wfrag, b_hh, W1, b1, W2, b2, dn, o);
}

// Round 10
// 146.106 us; speedup vs baseline: 1.2572x; 1.0453x over previous
//
#include <hip/hip_runtime.h>

#define NT 32768
#define DI 36
#define HH 64
#define G3 192
#define LH 20
#define SGS 196            // Sg row stride (floats), 16B-aligned, 2-way-bank-safe

#define NLOG2E -1.4426950408889634f   // r/z pre-scale: sigmoid(x)=rcp(1+exp2(-x*log2e))
#define TLOG2E 2.8853900817779268f    // n pre-scale: tanh(x)=1-2*rcp(1+exp2(2x*log2e))

// shared memory map (bytes):
//   [0, 27440)        Sg: float[35][196]  gi slice (fp32), wave-private by column
//   [27440, 41264)    union: { EmbH/EmbL bf16 staging (2x 48x72 ushort) } then
//                     { Hb[2][2][16*72] ushort h-exchange } (disjoint lifetimes)
//   [41264, 41328)    sfirst[16]
#define SG_BYTES   27440
#define UNION_OFF  27440
#define SFIRST_OFF 41264
#define SMEM_BYTES 41328

typedef __attribute__((ext_vector_type(8))) short bf16x8;
typedef __attribute__((ext_vector_type(4))) float f32x4;
typedef __attribute__((ext_vector_type(4))) int int4v;
union frag_cast { int4v i4; bf16x8 h8; };

__device__ __forceinline__ unsigned f2u(float f) { union { float f; unsigned u; } x; x.f = f; return x.u; }
__device__ __forceinline__ float u2f(unsigned u) { union { float f; unsigned u; } x; x.u = u; return x.f; }
__device__ __forceinline__ unsigned short f2bf_rne(float f) {
    union { float f; unsigned u; } x; x.f = f;
    unsigned r = x.u + 0x7FFFu + ((x.u >> 16) & 1u);
    return (unsigned short)(r >> 16);
}

// Single fused kernel: 2048 blocks x 256 thr (4 waves), 16 timesteps/block.
// Phase 1: in-block gi-GEMM (W_ih hi/lo x emb hi/lo, 54 MFMA/wave) -> Sg LDS.
// Phase 2: R9 recurrence (12 MFMA/step/wave, 4-way j-split, Hb dbl-buffer).
// Phase 3: R9 MLP. No prep kernel, no gi2 global round-trip.
__global__ __launch_bounds__(256, 3) void gru_kernel(
    const float* __restrict__ emb, const float* __restrict__ W_ih,
    const float* __restrict__ b_ih, const float* __restrict__ b_hh,
    const float* __restrict__ W_hh, const float* __restrict__ W1,
    const float* __restrict__ b1, const float* __restrict__ W2,
    const float* __restrict__ b2, const int* __restrict__ dones,
    float* __restrict__ out)
{
    __shared__ __align__(16) char SMEM[SMEM_BYTES];
    float* const Sg = (float*)SMEM;
    unsigned short* const EmbH = (unsigned short*)(SMEM + UNION_OFF);  // [48][72]
    unsigned short* const EmbL = EmbH + 48 * 72;
    unsigned short* const Hb   = (unsigned short*)(SMEM + UNION_OFF);  // alias
    int* const sfirst = (int*)(SMEM + SFIRST_OFF);

    const int tid = threadIdx.x;
    const int lane = tid & 63;
    const int W = tid >> 6;          // wave id = j-quarter owner
    const int li = lane & 15;        // t within group (MFMA col)
    const int q = lane >> 4;         // quad
    const int blk = ((int)blockIdx.x & 7) * 256 + ((int)blockIdx.x >> 3);
    const int T0 = blk * 16;
    const int t = T0 + li;

    // ---- Phase 0: stage emb window (bf16 hi/lo) + window starts ----
    {   // zero Emb staging (covers zero-pad rows 35..47 and k 36..63)
        int4v* z = (int4v*)EmbH;
        for (int i = tid; i < (48 * 72 * 2 * 2) / 16; i += 256) z[i] = int4v{0,0,0,0};
    }
    if (tid < 16) {                  // window start: dones[t-19..t-1] only
        const int tt = T0 + tid;
        int lo = tt - (LH - 1); if (lo < 0) lo = 0;
        int ws = lo;
        for (int j = lo; j < tt; ++j)
            ws = (dones[j] != 0) ? (j + 1) : ws;
        sfirst[tid] = ws - (tt - (LH - 1));
    }
    __syncthreads();
    for (int i = tid; i < 35 * DI; i += 256) {     // fill rows 0..34
        const int r = i / DI, c = i % DI;
        int tt = T0 - (LH - 1) + r; tt = tt < 0 ? 0 : tt;
        const float v = emb[(size_t)tt * DI + c];
        const unsigned u = f2u(v);
        const unsigned short hi = (unsigned short)(u >> 16);
        EmbH[r * 72 + c] = hi;
        EmbL[r * 72 + c] = (unsigned short)(f2u(v - u2f(u & 0xFFFF0000u)) >> 16);
    }

    // ---- W fragments in registers (L2-hot: every block reads same 44KB) ----
    // A-frag convention (verified R3): lane l holds A[m=16mt+(l&15)][k=32kt+8(l>>4)+jj]
    const int jrow = 16 * W + li;    // row within each gate's 64-row block
    bf16x8 aih[3][2], ail[3][2], whh[3][2];
#pragma unroll
    for (int g = 0; g < 3; ++g) {
        const float sc = (g < 2) ? NLOG2E : TLOG2E;
        const float* wi = W_ih + (size_t)(64 * g + jrow) * DI;
        const float* wh = W_hh + (size_t)(64 * g + jrow) * HH;
#pragma unroll
        for (int kt = 0; kt < 2; ++kt) {
            const int k0 = 32 * kt + 8 * q;
            unsigned short eh[8], el[8], ew[8];
#pragma unroll
            for (int jj = 0; jj < 8; ++jj) {
                const int k = k0 + jj;
                const float v = (k < DI) ? wi[k] * sc : 0.f;   // guarded (OOB at j=191)
                const unsigned u = f2u(v);
                eh[jj] = (unsigned short)(u >> 16);            // trunc hi
                el[jj] = (unsigned short)(f2u(v - u2f(u & 0xFFFF0000u)) >> 16);
                ew[jj] = f2bf_rne(wh[k] * sc);                 // W_hh hi-only (RNE)
            }
            frag_cast a, b, c;
            a.i4.x = eh[0] | ((unsigned)eh[1] << 16); a.i4.y = eh[2] | ((unsigned)eh[3] << 16);
            a.i4.z = eh[4] | ((unsigned)eh[5] << 16); a.i4.w = eh[6] | ((unsigned)eh[7] << 16);
            b.i4.x = el[0] | ((unsigned)el[1] << 16); b.i4.y = el[2] | ((unsigned)el[3] << 16);
            b.i4.z = el[4] | ((unsigned)el[5] << 16); b.i4.w = el[6] | ((unsigned)el[7] << 16);
            c.i4.x = ew[0] | ((unsigned)ew[1] << 16); c.i4.y = ew[2] | ((unsigned)ew[3] << 16);
            c.i4.z = ew[4] | ((unsigned)ew[5] << 16); c.i4.w = ew[6] | ((unsigned)ew[7] << 16);
            aih[g][kt] = a.h8; ail[g][kt] = b.h8; whh[g][kt] = c.h8;
        }
    }

    const int joff = 16 * W + 4 * q; // this thread's j' base within each gate
    f32x4 biasI[3];                  // gi-GEMM acc init = (b_ih + b_hh_rz) * sc
#pragma unroll
    for (int g = 0; g < 3; ++g) {
        const float sc = (g < 2) ? NLOG2E : TLOG2E;
        const f32x4 bi = *(const f32x4*)&b_ih[64 * g + joff];
        if (g < 2) {
            const f32x4 bh = *(const f32x4*)&b_hh[64 * g + joff];
#pragma unroll
            for (int rr = 0; rr < 4; ++rr) biasI[g][rr] = (bi[rr] + bh[rr]) * sc;
        } else {
#pragma unroll
            for (int rr = 0; rr < 4; ++rr) biasI[g][rr] = bi[rr] * sc;
        }
    }
    f32x4 bnv;                       // n-gate step init = 2*log2e * b_hh_n
    {
        const f32x4 b = *(const f32x4*)&b_hh[128 + joff];
#pragma unroll
        for (int rr = 0; rr < 4; ++rr) bnv[rr] = b[rr] * TLOG2E;
    }
    __syncthreads();                 // Emb staged

    // ---- Phase 1: gi-GEMM -> Sg (wave-private columns; same-wave FIFO) ----
#pragma unroll
    for (int nt = 0; nt < 3; ++nt) {
        bf16x8 ebh[2], ebl[2];
#pragma unroll
        for (int kt = 0; kt < 2; ++kt) {
            const int idx = (16 * nt + li) * 72 + 32 * kt + 8 * q;  // 16B-aligned
            ebh[kt] = *(const bf16x8*)&EmbH[idx];
            ebl[kt] = *(const bf16x8*)&EmbL[idx];
        }
#pragma unroll
        for (int g = 0; g < 3; ++g) {
            f32x4 a = biasI[g];
            a = __builtin_amdgcn_mfma_f32_16x16x32_bf16(aih[g][0], ebh[0], a, 0, 0, 0);
            a = __builtin_amdgcn_mfma_f32_16x16x32_bf16(aih[g][1], ebh[1], a, 0, 0, 0);
            a = __builtin_amdgcn_mfma_f32_16x16x32_bf16(ail[g][0], ebh[0], a, 0, 0, 0);
            a = __builtin_amdgcn_mfma_f32_16x16x32_bf16(ail[g][1], ebh[1], a, 0, 0, 0);
            a = __builtin_amdgcn_mfma_f32_16x16x32_bf16(aih[g][0], ebl[0], a, 0, 0, 0);
            a = __builtin_amdgcn_mfma_f32_16x16x32_bf16(aih[g][1], ebl[1], a, 0, 0, 0);
            const int row = 16 * nt + li;
            if (row < 35)
                *(f32x4*)&Sg[row * SGS + 64 * g + joff] = a;
        }
    }
    __syncthreads();                 // all waves past Emb reads (Hb aliases Emb)
    const int sfr = sfirst[li];

    // ---- Phase 2: recurrence (verbatim R9) ----
    unsigned short* const HbB = Hb;  // [buf][hl][16*72] shorts, buf stride 2304
    float h[4] = {0.f, 0.f, 0.f, 0.f};
    f32x4 accR, accZ, accN, ginv;

    {   // s = 0 (h=0: no MFMA), writes buf1 for s=1
        const float* gp = Sg + li * SGS;
        accR = *(const f32x4*)(gp + joff);
        accZ = *(const f32x4*)(gp + 64 + joff);
        ginv = *(const f32x4*)(gp + 128 + joff);
        accN = bnv;
        const bool valid = (0 >= sfr);
#pragma unroll
        for (int rr = 0; rr < 4; ++rr) {
            const float r  = __builtin_amdgcn_rcpf(1.f + __builtin_amdgcn_exp2f(accR[rr]));
            const float z  = __builtin_amdgcn_rcpf(1.f + __builtin_amdgcn_exp2f(accZ[rr]));
            const float nc = 1.f - 2.f * __builtin_amdgcn_rcpf(1.f + __builtin_amdgcn_exp2f(ginv[rr] + r * accN[rr]));
            h[rr] = valid ? fmaf(z, 0.f - nc, nc) : 0.f;
        }
        const unsigned u0 = f2u(h[0]), u1 = f2u(h[1]);
        const unsigned u2 = f2u(h[2]), u3 = f2u(h[3]);
        uint2 ph, pl;
        ph.x = __builtin_amdgcn_perm(u1, u0, 0x07060302u);
        ph.y = __builtin_amdgcn_perm(u3, u2, 0x07060302u);
        const unsigned l0 = f2u(h[0] - u2f(u0 & 0xFFFF0000u));
        const unsigned l1 = f2u(h[1] - u2f(u1 & 0xFFFF0000u));
        const unsigned l2 = f2u(h[2] - u2f(u2 & 0xFFFF0000u));
        const unsigned l3 = f2u(h[3] - u2f(u3 & 0xFFFF0000u));
        pl.x = __builtin_amdgcn_perm(l1, l0, 0x07060302u);
        pl.y = __builtin_amdgcn_perm(l3, l2, 0x07060302u);
        *(uint2*)&HbB[1 * 2304 + 0 * 1152 + li * 72 + joff] = ph;
        *(uint2*)&HbB[1 * 2304 + 1 * 1152 + li * 72 + joff] = pl;
    }
    __syncthreads();

#pragma unroll 2
    for (int s = 1; s < LH; ++s) {
        const int rb = s & 1;        // read buffer; write buffer = 1-rb
        const bf16x8 bh0 = *(const bf16x8*)&HbB[rb * 2304 + li * 72 + 8 * q];
        const bf16x8 bh1 = *(const bf16x8*)&HbB[rb * 2304 + li * 72 + 32 + 8 * q];
        const bf16x8 bl0 = *(const bf16x8*)&HbB[rb * 2304 + 1152 + li * 72 + 8 * q];
        const bf16x8 bl1 = *(const bf16x8*)&HbB[rb * 2304 + 1152 + li * 72 + 32 + 8 * q];

        const float* gp = Sg + (li + s) * SGS;     // LDS-only: cheap barrier drain
        accR = *(const f32x4*)(gp + joff);
        accZ = *(const f32x4*)(gp + 64 + joff);
        ginv = *(const f32x4*)(gp + 128 + joff);
        accN = bnv;

#pragma unroll
        for (int g = 0; g < 3; ++g) {
            f32x4 a = (g == 0) ? accR : (g == 1) ? accZ : accN;
            a = __builtin_amdgcn_mfma_f32_16x16x32_bf16(whh[g][0], bh0, a, 0, 0, 0);
            a = __builtin_amdgcn_mfma_f32_16x16x32_bf16(whh[g][1], bh1, a, 0, 0, 0);
            a = __builtin_amdgcn_mfma_f32_16x16x32_bf16(whh[g][0], bl0, a, 0, 0, 0);
            a = __builtin_amdgcn_mfma_f32_16x16x32_bf16(whh[g][1], bl1, a, 0, 0, 0);
            if (g == 0) accR = a; else if (g == 1) accZ = a; else accN = a;
        }
        const bool valid = (s >= sfr);
#pragma unroll
        for (int rr = 0; rr < 4; ++rr) {
            const float r  = __builtin_amdgcn_rcpf(1.f + __builtin_amdgcn_exp2f(accR[rr]));
            const float z  = __builtin_amdgcn_rcpf(1.f + __builtin_amdgcn_exp2f(accZ[rr]));
            const float nc = 1.f - 2.f * __builtin_amdgcn_rcpf(1.f + __builtin_amdgcn_exp2f(ginv[rr] + r * accN[rr]));
            const float hn = fmaf(z, h[rr] - nc, nc);
            h[rr] = valid ? hn : h[rr];
        }
        {
            const unsigned u0 = f2u(h[0]), u1 = f2u(h[1]);
            const unsigned u2 = f2u(h[2]), u3 = f2u(h[3]);
            uint2 ph, pl;
            ph.x = __builtin_amdgcn_perm(u1, u0, 0x07060302u);
            ph.y = __builtin_amdgcn_perm(u3, u2, 0x07060302u);
            const unsigned l0 = f2u(h[0] - u2f(u0 & 0xFFFF0000u));
            const unsigned l1 = f2u(h[1] - u2f(u1 & 0xFFFF0000u));
            const unsigned l2 = f2u(h[2] - u2f(u2 & 0xFFFF0000u));
            const unsigned l3 = f2u(h[3] - u2f(u3 & 0xFFFF0000u));
            pl.x = __builtin_amdgcn_perm(l1, l0, 0x07060302u);
            pl.y = __builtin_amdgcn_perm(l3, l2, 0x07060302u);
            *(uint2*)&HbB[(1 - rb) * 2304 + li * 72 + joff] = ph;
            *(uint2*)&HbB[(1 - rb) * 2304 + 1152 + li * 72 + joff] = pl;
        }
        __syncthreads();
    }

    // ---- Phase 3: MLP (reuse Sg as scratch) ----
    float* const Hf  = Sg;                       // [t][k] stride 68
    float* const Hid = Sg + 16 * 68;             // [t][m] stride 68
    {
        float4 st; st.x = h[0]; st.y = h[1]; st.z = h[2]; st.w = h[3];
        *(float4*)&Hf[li * 68 + joff] = st;
    }
    __syncthreads();
    {   // MLP1: lane = m, wave W handles t in [4W, 4W+4)
        float hid[4] = {0.f, 0.f, 0.f, 0.f};
        for (int k4 = 0; k4 < 16; ++k4) {
            const float4 wv = *(const float4*)&W1[lane * HH + 4 * k4];
#pragma unroll
            for (int tt = 0; tt < 4; ++tt) {
                const float4 hv = *(const float4*)&Hf[(4 * W + tt) * 68 + 4 * k4];
                hid[tt] += hv.x * wv.x + hv.y * wv.y + hv.z * wv.z + hv.w * wv.w;
            }
        }
        const float bb = b1[lane];
#pragma unroll
        for (int tt = 0; tt < 4; ++tt)
            Hid[(4 * W + tt) * 68 + lane] = fmaxf(hid[tt] + bb, 0.f);
    }
    __syncthreads();
    if (tid < 64) {                  // MLP2: thread (tid>>2 -> t, tid&3 -> c)
        const int tt = tid >> 2, c = tid & 3;
        float o2 = b2[c];
        for (int m4 = 0; m4 < 16; ++m4) {
            const float4 hv = *(const float4*)&Hid[tt * 68 + 4 * m4];
            const float4 wv = *(const float4*)&W2[c * HH + 4 * m4];
            o2 += hv.x * wv.x + hv.y * wv.y + hv.z * wv.z + hv.w * wv.w;
        }
        out[(size_t)(T0 + tt) * 4 + c] = o2;     // 256B contiguous
    }
}

extern "C" void kernel_launch(void* const* d_in, const int* in_sizes, int n_in,
                              void* d_out, int out_size, void* d_ws, size_t ws_size,
                              hipStream_t stream) {
    const float* emb  = (const float*)d_in[0];
    const float* W_ih = (const float*)d_in[1];
    const float* W_hh = (const float*)d_in[2];
    const float* b_ih = (const float*)d_in[3];
    const float* b_hh = (const float*)d_in[4];
    const float* W1   = (const float*)d_in[5];
    const float* b1   = (const float*)d_in[6];
    const float* W2   = (const float*)d_in[7];
    const float* b2   = (const float*)d_in[8];
    const int*   dn   = (const int*)d_in[9];
    float* o = (float*)d_out;

    gru_kernel<<<NT / 16, 256, 0, stream>>>(emb, W_ih, b_ih, b_hh, W_hh,
                                            W1, b1, W2, b2, dn, o);
}

// Round 11
// 133.543 us; speedup vs baseline: 1.3755x; 1.0941x over previous
//
#include <hip/hip_runtime.h>

#define NT 32768
#define DI 36
#define HH 64
#define G3 192
#define LH 20
#define SGS 196            // Sg row stride (floats), 16B-aligned

#define NLOG2E -1.4426950408889634f   // r/z pre-scale: sigmoid(x)=rcp(1+exp2(-x*log2e))
#define TLOG2E 2.8853900817779268f    // n pre-scale: tanh(x)=1-2*rcp(1+exp2(2x*log2e))

// shared memory map (bytes):
//   [0, 27440)        Sg: float[35][196]  gi slice (fp32), wave-private cols
//   [27440, 41264)    union: { EmbH/EmbL bf16 staging (2x 48x72 ushort) } then
//                     { Hb[2][2][16*72] ushort h-exchange } (disjoint lifetimes)
//   [41264, 41328)    sfirst[16]
#define UNION_OFF  27440
#define SFIRST_OFF 41264
#define SMEM_BYTES 41328

typedef __attribute__((ext_vector_type(8))) short bf16x8;
typedef __attribute__((ext_vector_type(4))) float f32x4;
typedef __attribute__((ext_vector_type(4))) int int4v;
union frag_cast { int4v i4; bf16x8 h8; };

__device__ __forceinline__ unsigned f2u(float f) { union { float f; unsigned u; } x; x.f = f; return x.u; }
__device__ __forceinline__ float u2f(unsigned u) { union { float f; unsigned u; } x; x.u = u; return x.f; }
__device__ __forceinline__ unsigned short f2bf_rne(float f) {
    union { float f; unsigned u; } x; x.f = f;
    unsigned r = x.u + 0x7FFFu + ((x.u >> 16) & 1u);
    return (unsigned short)(r >> 16);
}

// Tiny prep: emit pre-packed A-fragments so gru's prologue is 18 coalesced
// b128 loads instead of 96 scalar gathers per thread (R10's 30us prologue).
// set 0: W_ih hi (trunc), set 1: W_ih lo, set 2: W_hh hi (RNE). 24 frags/set.
// A-frag convention (verified R3): lane l holds A[m=16mt+(l&15)][k=32kt+8(l>>4)+jj].
__global__ __launch_bounds__(64) void prep_kernel(
    const float* __restrict__ W_ih, const float* __restrict__ W_hh,
    int4v* __restrict__ wfrag)
{
    const int b = (int)blockIdx.x;         // 0..71
    const int set = b / 24, fb = b % 24;
    const int mt = fb >> 1, kt = fb & 1;
    const int l = (int)threadIdx.x;
    const int m = mt * 16 + (l & 15);      // j row 0..191
    const int g = mt >> 2;                 // gate
    const float sc = (g < 2) ? NLOG2E : TLOG2E;
    const int k0 = kt * 32 + (l >> 4) * 8;
    unsigned short e[8];
#pragma unroll
    for (int jj = 0; jj < 8; ++jj) {
        const int k = k0 + jj;
        if (set == 2) {
            e[jj] = f2bf_rne(W_hh[(size_t)m * HH + k] * sc);
        } else {
            const float v = (k < DI) ? W_ih[(size_t)m * DI + k] * sc : 0.f;
            const unsigned u = f2u(v);
            if (set == 0) e[jj] = (unsigned short)(u >> 16);   // trunc hi
            else          e[jj] = (unsigned short)(f2u(v - u2f(u & 0xFFFF0000u)) >> 16);
        }
    }
    int4v p;
    p.x = e[0] | ((unsigned)e[1] << 16); p.y = e[2] | ((unsigned)e[3] << 16);
    p.z = e[4] | ((unsigned)e[5] << 16); p.w = e[6] | ((unsigned)e[7] << 16);
    wfrag[b * 64 + l] = p;
}

// Fused kernel: 2048 blocks x 256 thr (4 waves), 16 timesteps/block.
// Phase 1: in-block gi-GEMM (W_ih hi/lo x emb hi/lo) -> Sg LDS.
// Phase 2: recurrence, 4-way j-split, 12 MFMA/step/wave, LDS-only step loop.
// Phase 3: MLP. W fragments loaded coalesced from wfrag (L2-hot 73KB).
__global__ __launch_bounds__(256, 3) void gru_kernel(
    const float* __restrict__ emb, const int4v* __restrict__ wfrag,
    const float* __restrict__ b_ih, const float* __restrict__ b_hh,
    const float* __restrict__ W1, const float* __restrict__ b1,
    const float* __restrict__ W2, const float* __restrict__ b2,
    const int* __restrict__ dones, float* __restrict__ out)
{
    __shared__ __align__(16) char SMEM[SMEM_BYTES];
    float* const Sg = (float*)SMEM;
    unsigned short* const EmbH = (unsigned short*)(SMEM + UNION_OFF);  // [48][72]
    unsigned short* const EmbL = EmbH + 48 * 72;
    unsigned short* const HbB  = (unsigned short*)(SMEM + UNION_OFF);  // alias
    int* const sfirst = (int*)(SMEM + SFIRST_OFF);

    const int tid = threadIdx.x;
    const int lane = tid & 63;
    const int W = tid >> 6;          // wave id = j-quarter owner
    const int li = lane & 15;        // t within group (MFMA col)
    const int q = lane >> 4;         // quad
    const int blk = ((int)blockIdx.x & 7) * 256 + ((int)blockIdx.x >> 3);
    const int T0 = blk * 16;

    // ---- Phase 0: zero Emb staging, stage emb window, window starts ----
    {
        int4v* z = (int4v*)EmbH;
        for (int i = tid; i < (48 * 72 * 2 * 2) / 16; i += 256) z[i] = int4v{0,0,0,0};
    }
    if (tid < 16) {                  // window start: dones[t-19..t-1] only
        const int tt = T0 + tid;
        int lo = tt - (LH - 1); if (lo < 0) lo = 0;
        int ws = lo;
        for (int j = lo; j < tt; ++j)
            ws = (dones[j] != 0) ? (j + 1) : ws;
        sfirst[tid] = ws - (tt - (LH - 1));
    }
    __syncthreads();
    for (int i = tid; i < 35 * DI; i += 256) {     // fill rows 0..34
        const int r = i / DI, c = i % DI;
        int tt = T0 - (LH - 1) + r; tt = tt < 0 ? 0 : tt;
        const float v = emb[(size_t)tt * DI + c];
        const unsigned u = f2u(v);
        EmbH[r * 72 + c] = (unsigned short)(u >> 16);
        EmbL[r * 72 + c] = (unsigned short)(f2u(v - u2f(u & 0xFFFF0000u)) >> 16);
    }

    // ---- W fragments: 18 coalesced b128 loads (wave W -> tiles mt=4g+W) ----
    bf16x8 aih[3][2], ail[3][2], whh[3][2];
#pragma unroll
    for (int g = 0; g < 3; ++g)
#pragma unroll
        for (int kt = 0; kt < 2; ++kt) {
            const int fb = (4 * g + W) * 2 + kt;
            frag_cast a, b, c;
            a.i4 = wfrag[(0 * 24 + fb) * 64 + lane];
            b.i4 = wfrag[(1 * 24 + fb) * 64 + lane];
            c.i4 = wfrag[(2 * 24 + fb) * 64 + lane];
            aih[g][kt] = a.h8; ail[g][kt] = b.h8; whh[g][kt] = c.h8;
        }

    const int joff = 16 * W + 4 * q; // this thread's j' base within each gate
    f32x4 biasI[3];                  // gi-GEMM acc init = (b_ih + b_hh_rz) * sc
#pragma unroll
    for (int g = 0; g < 3; ++g) {
        const float sc = (g < 2) ? NLOG2E : TLOG2E;
        const f32x4 bi = *(const f32x4*)&b_ih[64 * g + joff];
        if (g < 2) {
            const f32x4 bh = *(const f32x4*)&b_hh[64 * g + joff];
#pragma unroll
            for (int rr = 0; rr < 4; ++rr) biasI[g][rr] = (bi[rr] + bh[rr]) * sc;
        } else {
#pragma unroll
            for (int rr = 0; rr < 4; ++rr) biasI[g][rr] = bi[rr] * sc;
        }
    }
    f32x4 bnv;                       // n-gate step init = 2*log2e * b_hh_n
    {
        const f32x4 b = *(const f32x4*)&b_hh[128 + joff];
#pragma unroll
        for (int rr = 0; rr < 4; ++rr) bnv[rr] = b[rr] * TLOG2E;
    }
    __syncthreads();                 // Emb staged

    // ---- Phase 1: gi-GEMM -> Sg (wave-private columns; same-wave FIFO) ----
#pragma unroll
    for (int nt = 0; nt < 3; ++nt) {
        bf16x8 ebh[2], ebl[2];
#pragma unroll
        for (int kt = 0; kt < 2; ++kt) {
            const int idx = (16 * nt + li) * 72 + 32 * kt + 8 * q;  // 16B-aligned
            ebh[kt] = *(const bf16x8*)&EmbH[idx];
            ebl[kt] = *(const bf16x8*)&EmbL[idx];
        }
#pragma unroll
        for (int g = 0; g < 3; ++g) {
            f32x4 a = biasI[g];
            a = __builtin_amdgcn_mfma_f32_16x16x32_bf16(aih[g][0], ebh[0], a, 0, 0, 0);
            a = __builtin_amdgcn_mfma_f32_16x16x32_bf16(aih[g][1], ebh[1], a, 0, 0, 0);
            a = __builtin_amdgcn_mfma_f32_16x16x32_bf16(ail[g][0], ebh[0], a, 0, 0, 0);
            a = __builtin_amdgcn_mfma_f32_16x16x32_bf16(ail[g][1], ebh[1], a, 0, 0, 0);
            a = __builtin_amdgcn_mfma_f32_16x16x32_bf16(aih[g][0], ebl[0], a, 0, 0, 0);
            a = __builtin_amdgcn_mfma_f32_16x16x32_bf16(aih[g][1], ebl[1], a, 0, 0, 0);
            const int row = 16 * nt + li;
            if (row < 35)
                *(f32x4*)&Sg[row * SGS + 64 * g + joff] = a;
        }
    }
    __syncthreads();                 // all waves past Emb reads (Hb aliases Emb)
    const int sfr = sfirst[li];

    // ---- Phase 2: recurrence ----
    float h[4] = {0.f, 0.f, 0.f, 0.f};
    f32x4 accR, accZ, accN, ginv;
    f32x4 gvR, gvZ, gvN;             // LDS->reg prefetch for step s+1

    {   // s = 0 (h=0: no MFMA), writes buf1 for s=1
        const float* gp = Sg + li * SGS;
        accR = *(const f32x4*)(gp + joff);
        accZ = *(const f32x4*)(gp + 64 + joff);
        ginv = *(const f32x4*)(gp + 128 + joff);
        accN = bnv;
        const bool valid = (0 >= sfr);
#pragma unroll
        for (int rr = 0; rr < 4; ++rr) {
            const float r  = __builtin_amdgcn_rcpf(1.f + __builtin_amdgcn_exp2f(accR[rr]));
            const float z  = __builtin_amdgcn_rcpf(1.f + __builtin_amdgcn_exp2f(accZ[rr]));
            const float nc = 1.f - 2.f * __builtin_amdgcn_rcpf(1.f + __builtin_amdgcn_exp2f(ginv[rr] + r * accN[rr]));
            h[rr] = valid ? fmaf(z, 0.f - nc, nc) : 0.f;
        }
        const unsigned u0 = f2u(h[0]), u1 = f2u(h[1]);
        const unsigned u2 = f2u(h[2]), u3 = f2u(h[3]);
        uint2 ph, pl;
        ph.x = __builtin_amdgcn_perm(u1, u0, 0x07060302u);
        ph.y = __builtin_amdgcn_perm(u3, u2, 0x07060302u);
        const unsigned l0 = f2u(h[0] - u2f(u0 & 0xFFFF0000u));
        const unsigned l1 = f2u(h[1] - u2f(u1 & 0xFFFF0000u));
        const unsigned l2 = f2u(h[2] - u2f(u2 & 0xFFFF0000u));
        const unsigned l3 = f2u(h[3] - u2f(u3 & 0xFFFF0000u));
        pl.x = __builtin_amdgcn_perm(l1, l0, 0x07060302u);
        pl.y = __builtin_amdgcn_perm(l3, l2, 0x07060302u);
        *(uint2*)&HbB[1 * 2304 + 0 * 1152 + li * 72 + joff] = ph;
        *(uint2*)&HbB[1 * 2304 + 1 * 1152 + li * 72 + joff] = pl;
        // prefetch gi for s=1
        const float* gq = Sg + (li + 1) * SGS;
        gvR = *(const f32x4*)(gq + joff);
        gvZ = *(const f32x4*)(gq + 64 + joff);
        gvN = *(const f32x4*)(gq + 128 + joff);
    }
    __syncthreads();

#pragma unroll 2
    for (int s = 1; s < LH; ++s) {
        const int rb = s & 1;        // read buffer; write buffer = 1-rb
        const bf16x8 bh0 = *(const bf16x8*)&HbB[rb * 2304 + li * 72 + 8 * q];
        const bf16x8 bh1 = *(const bf16x8*)&HbB[rb * 2304 + li * 72 + 32 + 8 * q];
        const bf16x8 bl0 = *(const bf16x8*)&HbB[rb * 2304 + 1152 + li * 72 + 8 * q];
        const bf16x8 bl1 = *(const bf16x8*)&HbB[rb * 2304 + 1152 + li * 72 + 32 + 8 * q];

        accR = gvR; accZ = gvZ; ginv = gvN; accN = bnv;
        {   // prefetch s+1's gi (row clamped; s=19 value unused)
            int r = li + s + 1; r = r > 34 ? 34 : r;
            const float* gq = Sg + r * SGS;
            gvR = *(const f32x4*)(gq + joff);
            gvZ = *(const f32x4*)(gq + 64 + joff);
            gvN = *(const f32x4*)(gq + 128 + joff);
        }
#pragma unroll
        for (int g = 0; g < 3; ++g) {
            f32x4 a = (g == 0) ? accR : (g == 1) ? accZ : accN;
            a = __builtin_amdgcn_mfma_f32_16x16x32_bf16(whh[g][0], bh0, a, 0, 0, 0);
            a = __builtin_amdgcn_mfma_f32_16x16x32_bf16(whh[g][1], bh1, a, 0, 0, 0);
            a = __builtin_amdgcn_mfma_f32_16x16x32_bf16(whh[g][0], bl0, a, 0, 0, 0);
            a = __builtin_amdgcn_mfma_f32_16x16x32_bf16(whh[g][1], bl1, a, 0, 0, 0);
            if (g == 0) accR = a; else if (g == 1) accZ = a; else accN = a;
        }
        const bool valid = (s >= sfr);
#pragma unroll
        for (int rr = 0; rr < 4; ++rr) {
            const float r  = __builtin_amdgcn_rcpf(1.f + __builtin_amdgcn_exp2f(accR[rr]));
            const float z  = __builtin_amdgcn_rcpf(1.f + __builtin_amdgcn_exp2f(accZ[rr]));
            const float nc = 1.f - 2.f * __builtin_amdgcn_rcpf(1.f + __builtin_amdgcn_exp2f(ginv[rr] + r * accN[rr]));
            const float hn = fmaf(z, h[rr] - nc, nc);
            h[rr] = valid ? hn : h[rr];
        }
        {
            const unsigned u0 = f2u(h[0]), u1 = f2u(h[1]);
            const unsigned u2 = f2u(h[2]), u3 = f2u(h[3]);
            uint2 ph, pl;
            ph.x = __builtin_amdgcn_perm(u1, u0, 0x07060302u);
            ph.y = __builtin_amdgcn_perm(u3, u2, 0x07060302u);
            const unsigned l0 = f2u(h[0] - u2f(u0 & 0xFFFF0000u));
            const unsigned l1 = f2u(h[1] - u2f(u1 & 0xFFFF0000u));
            const unsigned l2 = f2u(h[2] - u2f(u2 & 0xFFFF0000u));
            const unsigned l3 = f2u(h[3] - u2f(u3 & 0xFFFF0000u));
            pl.x = __builtin_amdgcn_perm(l1, l0, 0x07060302u);
            pl.y = __builtin_amdgcn_perm(l3, l2, 0x07060302u);
            *(uint2*)&HbB[(1 - rb) * 2304 + li * 72 + joff] = ph;
            *(uint2*)&HbB[(1 - rb) * 2304 + 1152 + li * 72 + joff] = pl;
        }
        __syncthreads();             // LDS-only drain (cheap)
    }

    // ---- Phase 3: MLP (reuse Sg as scratch) ----
    float* const Hf  = Sg;                       // [t][k] stride 68
    float* const Hid = Sg + 16 * 68;             // [t][m] stride 68
    {
        float4 st; st.x = h[0]; st.y = h[1]; st.z = h[2]; st.w = h[3];
        *(float4*)&Hf[li * 68 + joff] = st;
    }
    __syncthreads();
    {   // MLP1: lane = m, wave W handles t in [4W, 4W+4)
        float hid[4] = {0.f, 0.f, 0.f, 0.f};
        for (int k4 = 0; k4 < 16; ++k4) {
            const float4 wv = *(const float4*)&W1[lane * HH + 4 * k4];
#pragma unroll
            for (int tt = 0; tt < 4; ++tt) {
                const float4 hv = *(const float4*)&Hf[(4 * W + tt) * 68 + 4 * k4];
                hid[tt] += hv.x * wv.x + hv.y * wv.y + hv.z * wv.z + hv.w * wv.w;
            }
        }
        const float bb = b1[lane];
#pragma unroll
        for (int tt = 0; tt < 4; ++tt)
            Hid[(4 * W + tt) * 68 + lane] = fmaxf(hid[tt] + bb, 0.f);
    }
    __syncthreads();
    if (tid < 64) {                  // MLP2: thread (tid>>2 -> t, tid&3 -> c)
        const int tt = tid >> 2, c = tid & 3;
        float o2 = b2[c];
        for (int m4 = 0; m4 < 16; ++m4) {
            const float4 hv = *(const float4*)&Hid[tt * 68 + 4 * m4];
            const float4 wv = *(const float4*)&W2[c * HH + 4 * m4];
            o2 += hv.x * wv.x + hv.y * wv.y + hv.z * wv.z + hv.w * wv.w;
        }
        out[(size_t)(T0 + tt) * 4 + c] = o2;     // 256B contiguous
    }
}

extern "C" void kernel_launch(void* const* d_in, const int* in_sizes, int n_in,
                              void* d_out, int out_size, void* d_ws, size_t ws_size,
                              hipStream_t stream) {
    const float* emb  = (const float*)d_in[0];
    const float* W_ih = (const float*)d_in[1];
    const float* W_hh = (const float*)d_in[2];
    const float* b_ih = (const float*)d_in[3];
    const float* b_hh = (const float*)d_in[4];
    const float* W1   = (const float*)d_in[5];
    const float* b1   = (const float*)d_in[6];
    const float* W2   = (const float*)d_in[7];
    const float* b2   = (const float*)d_in[8];
    const int*   dn   = (const int*)d_in[9];

    int4v* wfrag = (int4v*)d_ws;     // 72 frags x 64 lanes x 16B = 73.7 KB
    float* o = (float*)d_out;

    prep_kernel<<<72, 64, 0, stream>>>(W_ih, W_hh, wfrag);
    gru_kernel<<<NT / 16, 256, 0, stream>>>(emb, wfrag, b_ih, b_hh,
                                            W1, b1, W2, b2, dn, o);
}

// Round 12
// 114.800 us; speedup vs baseline: 1.6001x; 1.1633x over previous
//
#include <hip/hip_runtime.h>

#define NT 32768
#define DI 36
#define HH 64
#define G3 192
#define LH 20
#define SGS 196            // Sg row stride (floats), 16B-aligned

#define NLOG2E -1.4426950408889634f   // r/z pre-scale: sigmoid(x)=rcp(1+exp2(-x*log2e))
#define TLOG2E 2.8853900817779268f    // n pre-scale: tanh(x)=1-2*rcp(1+exp2(2x*log2e))

// shared memory map (bytes):
//   [0, 27440)          Sg: float[35][196] gi slice (fp32), wave-private cols;
//                       reused as Hid[16][68] for the MLP epilogue
//   [27440, 39728)      union: { EmbH/EmbL bf16 staging, 2 x [48][64] ushort }
//                       then { Hb[2][16*72] ushort h-hi exchange } then
//                       { HfH/HfL final-h hi/lo planes } (disjoint lifetimes)
//   [39728, 39792)      sfirst[16]
#define UNION_OFF  27440
#define SFIRST_OFF 39728
#define SMEM_BYTES 39792   // < 40KB -> 4 blocks/CU

typedef __attribute__((ext_vector_type(8))) short bf16x8;
typedef __attribute__((ext_vector_type(4))) float f32x4;
typedef __attribute__((ext_vector_type(4))) int int4v;
union frag_cast { int4v i4; bf16x8 h8; };

__device__ __forceinline__ unsigned f2u(float f) { union { float f; unsigned u; } x; x.f = f; return x.u; }
__device__ __forceinline__ float u2f(unsigned u) { union { float f; unsigned u; } x; x.u = u; return x.f; }
__device__ __forceinline__ unsigned short f2bf_rne(float f) {
    union { float f; unsigned u; } x; x.f = f;
    unsigned r = x.u + 0x7FFFu + ((x.u >> 16) & 1u);
    return (unsigned short)(r >> 16);
}

// Prep: pre-packed A-fragments, coalesced-consumable by gru.
// frags 0..23: W_ih hi (trunc, scaled) | 24..47: W_ih lo | 48..71: W_hh hi (RNE, scaled)
// frags 72..79: W1 hi (trunc) | 80..87: W1 lo
// A-frag convention (verified R3): lane l holds A[m=16mt+(l&15)][k=32kt+8(l>>4)+jj].
__global__ __launch_bounds__(64) void prep_kernel(
    const float* __restrict__ W_ih, const float* __restrict__ W_hh,
    const float* __restrict__ W1, int4v* __restrict__ wfrag)
{
    const int b = (int)blockIdx.x;         // 0..87
    const int l = (int)threadIdx.x;
    unsigned short e[8];
    if (b < 72) {
        const int set = b / 24, fb = b % 24;
        const int mt = fb >> 1, kt = fb & 1;
        const int m = mt * 16 + (l & 15);  // j row 0..191
        const float sc = ((mt >> 2) < 2) ? NLOG2E : TLOG2E;
        const int k0 = kt * 32 + (l >> 4) * 8;
#pragma unroll
        for (int jj = 0; jj < 8; ++jj) {
            const int k = k0 + jj;
            if (set == 2) {
                e[jj] = f2bf_rne(W_hh[(size_t)m * HH + k] * sc);
            } else {
                const float v = (k < DI) ? W_ih[(size_t)m * DI + k] * sc : 0.f;
                const unsigned u = f2u(v);
                if (set == 0) e[jj] = (unsigned short)(u >> 16);   // trunc hi
                else          e[jj] = (unsigned short)(f2u(v - u2f(u & 0xFFFF0000u)) >> 16);
            }
        }
    } else {
        const int bb = b - 72;             // 0..15
        const bool is_lo = bb >= 8;
        const int f = bb & 7;
        const int mt = f >> 1, kt = f & 1;
        const int m = mt * 16 + (l & 15);  // 0..63
        const int k0 = kt * 32 + (l >> 4) * 8;
#pragma unroll
        for (int jj = 0; jj < 8; ++jj) {
            const float v = W1[(size_t)m * HH + k0 + jj];
            const unsigned u = f2u(v);
            if (!is_lo) e[jj] = (unsigned short)(u >> 16);         // trunc hi
            else        e[jj] = (unsigned short)(f2u(v - u2f(u & 0xFFFF0000u)) >> 16);
        }
    }
    int4v p;
    p.x = e[0] | ((unsigned)e[1] << 16); p.y = e[2] | ((unsigned)e[3] << 16);
    p.z = e[4] | ((unsigned)e[5] << 16); p.w = e[6] | ((unsigned)e[7] << 16);
    wfrag[b * 64 + l] = p;
}

// Fused kernel: 2048 blocks x 256 thr (4 waves), 16 timesteps/block.
// Phase 1: in-block gi-GEMM (W_ih hi/lo x emb hi/lo) -> Sg LDS.
// Phase 2: recurrence, 4-way j-split; h carried bf16-HI-only into MFMA
//          (fp32 h in regs): 6 MFMA + 2 b128 + 1 b64-write per wave-step.
// Phase 3: MLP1 via MFMA (h hi/lo exact), MLP2 scalar.
__global__ __launch_bounds__(256, 4) void gru_kernel(
    const float* __restrict__ emb, const int4v* __restrict__ wfrag,
    const float* __restrict__ b_ih, const float* __restrict__ b_hh,
    const float* __restrict__ b1, const float* __restrict__ W2,
    const float* __restrict__ b2, const int* __restrict__ dones,
    float* __restrict__ out)
{
    __shared__ __align__(16) char SMEM[SMEM_BYTES];
    float* const Sg = (float*)SMEM;
    unsigned short* const EmbH = (unsigned short*)(SMEM + UNION_OFF);  // [48][64]
    unsigned short* const EmbL = EmbH + 48 * 64;
    unsigned short* const HbB  = (unsigned short*)(SMEM + UNION_OFF);  // [2][1152]
    unsigned short* const HfH  = (unsigned short*)(SMEM + UNION_OFF);  // [16][72]
    unsigned short* const HfL  = HfH + 1152;
    int* const sfirst = (int*)(SMEM + SFIRST_OFF);

    const int tid = threadIdx.x;
    const int lane = tid & 63;
    const int W = tid >> 6;          // wave id = j-quarter owner
    const int li = lane & 15;        // t within group (MFMA col)
    const int q = lane >> 4;         // quad
    const int blk = ((int)blockIdx.x & 7) * 256 + ((int)blockIdx.x >> 3);
    const int T0 = blk * 16;

    // ---- Phase 0: zero Emb staging, stage emb window, window starts ----
    {
        int4v* z = (int4v*)EmbH;
        for (int i = tid; i < 768; i += 256) z[i] = int4v{0, 0, 0, 0};
    }
    if (tid < 16) {                  // window start: dones[t-19..t-1] only
        const int tt = T0 + tid;
        int lo = tt - (LH - 1); if (lo < 0) lo = 0;
        int ws = lo;
        for (int j = lo; j < tt; ++j)
            ws = (dones[j] != 0) ? (j + 1) : ws;
        sfirst[tid] = ws - (tt - (LH - 1));
    }
    __syncthreads();
    for (int i = tid; i < 35 * DI; i += 256) {     // fill rows 0..34
        const int r = i / DI, c = i % DI;
        int tt = T0 - (LH - 1) + r; tt = tt < 0 ? 0 : tt;
        const float v = emb[(size_t)tt * DI + c];
        const unsigned u = f2u(v);
        EmbH[r * 64 + c] = (unsigned short)(u >> 16);
        EmbL[r * 64 + c] = (unsigned short)(f2u(v - u2f(u & 0xFFFF0000u)) >> 16);
    }

    // ---- W fragments: 18 coalesced b128 loads (wave W -> tiles mt=4g+W) ----
    bf16x8 aih[3][2], ail[3][2], whh[3][2];
#pragma unroll
    for (int g = 0; g < 3; ++g)
#pragma unroll
        for (int kt = 0; kt < 2; ++kt) {
            const int fb = (4 * g + W) * 2 + kt;
            frag_cast a, b, c;
            a.i4 = wfrag[(0 * 24 + fb) * 64 + lane];
            b.i4 = wfrag[(1 * 24 + fb) * 64 + lane];
            c.i4 = wfrag[(2 * 24 + fb) * 64 + lane];
            aih[g][kt] = a.h8; ail[g][kt] = b.h8; whh[g][kt] = c.h8;
        }

    const int joff = 16 * W + 4 * q; // this thread's j' base within each gate
    f32x4 biasI[3];                  // gi-GEMM acc init = (b_ih + b_hh_rz) * sc
#pragma unroll
    for (int g = 0; g < 3; ++g) {
        const float sc = (g < 2) ? NLOG2E : TLOG2E;
        const f32x4 bi = *(const f32x4*)&b_ih[64 * g + joff];
        if (g < 2) {
            const f32x4 bh = *(const f32x4*)&b_hh[64 * g + joff];
#pragma unroll
            for (int rr = 0; rr < 4; ++rr) biasI[g][rr] = (bi[rr] + bh[rr]) * sc;
        } else {
#pragma unroll
            for (int rr = 0; rr < 4; ++rr) biasI[g][rr] = bi[rr] * sc;
        }
    }
    f32x4 bnv;                       // n-gate step init = 2*log2e * b_hh_n
    {
        const f32x4 b = *(const f32x4*)&b_hh[128 + joff];
#pragma unroll
        for (int rr = 0; rr < 4; ++rr) bnv[rr] = b[rr] * TLOG2E;
    }
    __syncthreads();                 // Emb staged

    // ---- Phase 1: gi-GEMM -> Sg (wave-private columns; same-wave FIFO) ----
#pragma unroll
    for (int nt = 0; nt < 3; ++nt) {
        bf16x8 ebh[2], ebl[2];
#pragma unroll
        for (int kt = 0; kt < 2; ++kt) {
            const int idx = (16 * nt + li) * 64 + 32 * kt + 8 * q;  // 16B-aligned
            ebh[kt] = *(const bf16x8*)&EmbH[idx];
            ebl[kt] = *(const bf16x8*)&EmbL[idx];
        }
#pragma unroll
        for (int g = 0; g < 3; ++g) {
            f32x4 a = biasI[g];
            a = __builtin_amdgcn_mfma_f32_16x16x32_bf16(aih[g][0], ebh[0], a, 0, 0, 0);
            a = __builtin_amdgcn_mfma_f32_16x16x32_bf16(aih[g][1], ebh[1], a, 0, 0, 0);
            a = __builtin_amdgcn_mfma_f32_16x16x32_bf16(ail[g][0], ebh[0], a, 0, 0, 0);
            a = __builtin_amdgcn_mfma_f32_16x16x32_bf16(ail[g][1], ebh[1], a, 0, 0, 0);
            a = __builtin_amdgcn_mfma_f32_16x16x32_bf16(aih[g][0], ebl[0], a, 0, 0, 0);
            a = __builtin_amdgcn_mfma_f32_16x16x32_bf16(aih[g][1], ebl[1], a, 0, 0, 0);
            const int row = 16 * nt + li;
            if (row < 35)
                *(f32x4*)&Sg[row * SGS + 64 * g + joff] = a;
        }
    }
    __syncthreads();                 // all waves past Emb reads (Hb aliases Emb)
    const int sfr = sfirst[li];

    // ---- Phase 2: recurrence (h-hi only through MFMA) ----
    float h[4] = {0.f, 0.f, 0.f, 0.f};
    f32x4 accR, accZ, accN, ginv;
    f32x4 gvR, gvZ, gvN;             // LDS->reg prefetch for step s+1

    {   // s = 0 (h=0: no MFMA), writes buf1 for s=1
        const float* gp = Sg + li * SGS;
        accR = *(const f32x4*)(gp + joff);
        accZ = *(const f32x4*)(gp + 64 + joff);
        ginv = *(const f32x4*)(gp + 128 + joff);
        accN = bnv;
        const bool valid = (0 >= sfr);
#pragma unroll
        for (int rr = 0; rr < 4; ++rr) {
            const float r  = __builtin_amdgcn_rcpf(1.f + __builtin_amdgcn_exp2f(accR[rr]));
            const float z  = __builtin_amdgcn_rcpf(1.f + __builtin_amdgcn_exp2f(accZ[rr]));
            const float nc = 1.f - 2.f * __builtin_amdgcn_rcpf(1.f + __builtin_amdgcn_exp2f(ginv[rr] + r * accN[rr]));
            h[rr] = valid ? fmaf(z, 0.f - nc, nc) : 0.f;
        }
        uint2 ph;
        ph.x = __builtin_amdgcn_perm(f2u(h[1]), f2u(h[0]), 0x07060302u);
        ph.y = __builtin_amdgcn_perm(f2u(h[3]), f2u(h[2]), 0x07060302u);
        *(uint2*)&HbB[1152 + li * 72 + joff] = ph;
        // prefetch gi for s=1
        const float* gq = Sg + (li + 1) * SGS;
        gvR = *(const f32x4*)(gq + joff);
        gvZ = *(const f32x4*)(gq + 64 + joff);
        gvN = *(const f32x4*)(gq + 128 + joff);
    }
    __syncthreads();

#pragma unroll 2
    for (int s = 1; s < LH; ++s) {
        const int rb = s & 1;        // read buffer; write buffer = 1-rb
        const bf16x8 bh0 = *(const bf16x8*)&HbB[rb * 1152 + li * 72 + 8 * q];
        const bf16x8 bh1 = *(const bf16x8*)&HbB[rb * 1152 + li * 72 + 32 + 8 * q];

        accR = gvR; accZ = gvZ; ginv = gvN; accN = bnv;
        {   // prefetch s+1's gi (row clamped; s=19 value unused)
            int r = li + s + 1; r = r > 34 ? 34 : r;
            const float* gq = Sg + r * SGS;
            gvR = *(const f32x4*)(gq + joff);
            gvZ = *(const f32x4*)(gq + 64 + joff);
            gvN = *(const f32x4*)(gq + 128 + joff);
        }
#pragma unroll
        for (int g = 0; g < 3; ++g) {
            f32x4 a = (g == 0) ? accR : (g == 1) ? accZ : accN;
            a = __builtin_amdgcn_mfma_f32_16x16x32_bf16(whh[g][0], bh0, a, 0, 0, 0);
            a = __builtin_amdgcn_mfma_f32_16x16x32_bf16(whh[g][1], bh1, a, 0, 0, 0);
            if (g == 0) accR = a; else if (g == 1) accZ = a; else accN = a;
        }
        const bool valid = (s >= sfr);
#pragma unroll
        for (int rr = 0; rr < 4; ++rr) {
            const float r  = __builtin_amdgcn_rcpf(1.f + __builtin_amdgcn_exp2f(accR[rr]));
            const float z  = __builtin_amdgcn_rcpf(1.f + __builtin_amdgcn_exp2f(accZ[rr]));
            const float nc = 1.f - 2.f * __builtin_amdgcn_rcpf(1.f + __builtin_amdgcn_exp2f(ginv[rr] + r * accN[rr]));
            const float hn = fmaf(z, h[rr] - nc, nc);
            h[rr] = valid ? hn : h[rr];
        }
        if (s != LH - 1) {
            uint2 ph;
            ph.x = __builtin_amdgcn_perm(f2u(h[1]), f2u(h[0]), 0x07060302u);
            ph.y = __builtin_amdgcn_perm(f2u(h[3]), f2u(h[2]), 0x07060302u);
            *(uint2*)&HbB[(1 - rb) * 1152 + li * 72 + joff] = ph;
        }
        __syncthreads();             // LDS-only drain (cheap)
    }

    // ---- Phase 3: MLP. Final h -> hi/lo planes (exact), MLP1 via MFMA ----
    {
        const unsigned u0 = f2u(h[0]), u1 = f2u(h[1]);
        const unsigned u2 = f2u(h[2]), u3 = f2u(h[3]);
        uint2 ph, pl;
        ph.x = __builtin_amdgcn_perm(u1, u0, 0x07060302u);
        ph.y = __builtin_amdgcn_perm(u3, u2, 0x07060302u);
        const unsigned l0 = f2u(h[0] - u2f(u0 & 0xFFFF0000u));
        const unsigned l1 = f2u(h[1] - u2f(u1 & 0xFFFF0000u));
        const unsigned l2 = f2u(h[2] - u2f(u2 & 0xFFFF0000u));
        const unsigned l3 = f2u(h[3] - u2f(u3 & 0xFFFF0000u));
        pl.x = __builtin_amdgcn_perm(l1, l0, 0x07060302u);
        pl.y = __builtin_amdgcn_perm(l3, l2, 0x07060302u);
        *(uint2*)&HfH[li * 72 + joff] = ph;
        *(uint2*)&HfL[li * 72 + joff] = pl;
    }
    __syncthreads();
    {   // MLP1: wave W computes hid[m=16W+4q+rr][t=li] via 6 MFMA
        bf16x8 w1h[2], w1l[2];
#pragma unroll
        for (int kt = 0; kt < 2; ++kt) {
            frag_cast a, b;
            a.i4 = wfrag[(72 + W * 2 + kt) * 64 + lane];
            b.i4 = wfrag[(80 + W * 2 + kt) * 64 + lane];
            w1h[kt] = a.h8; w1l[kt] = b.h8;
        }
        const bf16x8 bh0 = *(const bf16x8*)&HfH[li * 72 + 8 * q];
        const bf16x8 bh1 = *(const bf16x8*)&HfH[li * 72 + 32 + 8 * q];
        const bf16x8 bl0 = *(const bf16x8*)&HfL[li * 72 + 8 * q];
        const bf16x8 bl1 = *(const bf16x8*)&HfL[li * 72 + 32 + 8 * q];
        f32x4 a = *(const f32x4*)&b1[joff];
        a = __builtin_amdgcn_mfma_f32_16x16x32_bf16(w1h[0], bh0, a, 0, 0, 0);
        a = __builtin_amdgcn_mfma_f32_16x16x32_bf16(w1h[1], bh1, a, 0, 0, 0);
        a = __builtin_amdgcn_mfma_f32_16x16x32_bf16(w1l[0], bh0, a, 0, 0, 0);
        a = __builtin_amdgcn_mfma_f32_16x16x32_bf16(w1l[1], bh1, a, 0, 0, 0);
        a = __builtin_amdgcn_mfma_f32_16x16x32_bf16(w1h[0], bl0, a, 0, 0, 0);
        a = __builtin_amdgcn_mfma_f32_16x16x32_bf16(w1h[1], bl1, a, 0, 0, 0);
        __syncthreads();             // HfH/HfL reads done (Hid aliases Sg, not Hf — but keep order tight)
        float4 st;
        st.x = fmaxf(a[0], 0.f); st.y = fmaxf(a[1], 0.f);
        st.z = fmaxf(a[2], 0.f); st.w = fmaxf(a[3], 0.f);
        *(float4*)&Sg[li * 68 + joff] = st;      // Hid[t][m] stride 68
    }
    __syncthreads();
    if (tid < 64) {                  // MLP2: thread (tid>>2 -> t, tid&3 -> c)
        const int tt = tid >> 2, c = tid & 3;
        float o2 = b2[c];
        for (int m4 = 0; m4 < 16; ++m4) {
            const float4 hv = *(const float4*)&Sg[tt * 68 + 4 * m4];
            const float4 wv = *(const float4*)&W2[c * HH + 4 * m4];
            o2 += hv.x * wv.x + hv.y * wv.y + hv.z * wv.z + hv.w * wv.w;
        }
        out[(size_t)(T0 + tt) * 4 + c] = o2;     // 256B contiguous
    }
}

extern "C" void kernel_launch(void* const* d_in, const int* in_sizes, int n_in,
                              void* d_out, int out_size, void* d_ws, size_t ws_size,
                              hipStream_t stream) {
    const float* emb  = (const float*)d_in[0];
    const float* W_ih = (const float*)d_in[1];
    const float* W_hh = (const float*)d_in[2];
    const float* b_ih = (const float*)d_in[3];
    const float* b_hh = (const float*)d_in[4];
    const float* W1   = (const float*)d_in[5];
    const float* b1   = (const float*)d_in[6];
    const float* W2   = (const float*)d_in[7];
    const float* b2   = (const float*)d_in[8];
    const int*   dn   = (const int*)d_in[9];

    int4v* wfrag = (int4v*)d_ws;     // 88 frags x 64 lanes x 16B = 90 KB
    float* o = (float*)d_out;

    prep_kernel<<<88, 64, 0, stream>>>(W_ih, W_hh, W1, wfrag);
    gru_kernel<<<NT / 16, 256, 0, stream>>>(emb, wfrag, b_ih, b_hh,
                                            b1, W2, b2, dn, o);
}